// Round 7
// baseline (695.158 us; speedup 1.0000x reference)
//
#include <hip/hip_runtime.h>
#include <cstdint>

// ---------------------------------------------------------------------------
// FP8TransformerLayer on MI355X (gfx950) — round 11: unified BK=64
// double-buffered counted-vmcnt GEMM. All prior rounds show every GEMM at
// MfmaUtil ~12% / Occ ~21% (latency-bound). gemm_simple had TLP (4 blk/CU)
// but per-tile vmcnt(0) drains; gemm_pipe had ILP but 72-96KB LDS killed TLP.
// BK=64 gives both: 2x16KB tile buffers + scale slab = 40KB (K=2048) /
// 64KB (fc2) -> 4 blocks/CU kept, vmcnt(4) counted pipeline (never 0
// mid-loop). Scale fold per 64-K step (keeps chk lifetime within a step ->
// VGPR<=128, avoiding the r9 occupancy cliff; few-ULP reassociation vs
// fold-per-128, absmax unaffected at ~0.0527). Attention (256,2)+setprio,
// LN/quant unchanged from r10.
// B=2 T=1024 C=2048 H=16 HD=128 MLP=8192, BS=128 quant blocks.
// ---------------------------------------------------------------------------

typedef __bf16 bf16x8 __attribute__((ext_vector_type(8)));
typedef unsigned short u16x8 __attribute__((ext_vector_type(8)));
typedef float f32x4 __attribute__((ext_vector_type(4)));
typedef float f32x16 __attribute__((ext_vector_type(16)));
typedef int i32x8 __attribute__((ext_vector_type(8)));
typedef unsigned short u16;

#if __has_builtin(__builtin_amdgcn_exp2f)
#define EXP2F(x) __builtin_amdgcn_exp2f(x)
#else
#define EXP2F(x) exp2f(x)
#endif

#define CFENCE() asm volatile("" ::: "memory")

__device__ __forceinline__ void gl_lds16(const void* g, void* l) {
  __builtin_amdgcn_global_load_lds(
      (const __attribute__((address_space(1))) void*)g,
      (__attribute__((address_space(3))) void*)l, 16, 0, 0);
}

struct u4x2 { uint4 a, b; };
__device__ __forceinline__ i32x8 pack8(uint4 lo, uint4 hi) {
  u4x2 t{lo, hi};
  return __builtin_bit_cast(i32x8, t);
}

__device__ __forceinline__ u16 bf16_rne(float v) {
  uint32_t u = __float_as_uint(v);
  u += 0x7FFFu + ((u >> 16) & 1u);
  return (u16)(u >> 16);
}

__device__ __forceinline__ float fp8_round(float v, int mbits, float minnorm, float subq) {
  float av = fabsf(v);
  if (av < minnorm) {
    return rintf(v / subq) * subq;  // subnormal grid, RNE
  }
  uint32_t u = __float_as_uint(v);
  const int shift = 23 - mbits;
  const uint32_t mask = (1u << shift) - 1u;
  const uint32_t rem = u & mask;
  uint32_t base = u & ~mask;
  const uint32_t half = 1u << (shift - 1);
  if (rem > half || (rem == half && ((base >> shift) & 1u))) base += (1u << shift);
  return __uint_as_float(base);
}

// exact byte encode of an fp8-representable f32 (e4m3fn: mbits=3,bias=7;
// e5m2: mbits=2,bias=15)
__device__ __forceinline__ uint8_t fp8_encode(float v, int mbits, int bias) {
  uint32_t u = __float_as_uint(v);
  uint32_t sign = (u >> 31) << 7;
  if ((u & 0x7FFFFFFFu) == 0) return (uint8_t)sign;
  int e = (int)((u >> 23) & 255u) - 127;
  if (e >= 1 - bias) {
    uint32_t mant = (u >> (23 - mbits)) & ((1u << mbits) - 1u);
    return (uint8_t)(sign | ((uint32_t)(e + bias) << mbits) | mant);
  }
  // subnormal: |v| * 2^(bias-1+mbits) is an exact small integer
  float q = fabsf(v) * __uint_as_float((uint32_t)(127 + bias - 1 + mbits) << 23);
  return (uint8_t)(sign | (uint32_t)q);
}

// one 64-lane wave per 128-element quant block; fp8 BYTES out; scale written
// TRANSPOSED: sT[kb * Mtot + m], kb = wid & (kbs-1), m = wid >> kbshift.
__global__ __launch_bounds__(256) void qdq_kernel(
    const float* __restrict__ x, uint8_t* __restrict__ q, float* __restrict__ sT,
    int nblk, int kbshift, float fmax, float minnorm, float subq, int mbits, int bias) {
  const int wid = blockIdx.x * 4 + (threadIdx.x >> 6);
  if (wid >= nblk) return;
  const int lane = threadIdx.x & 63;
  const size_t base = (size_t)wid * 128 + (size_t)lane * 2;
  float2 v = *(const float2*)(x + base);
  float am = fmaxf(fabsf(v.x), fabsf(v.y));
#pragma unroll
  for (int m = 32; m >= 1; m >>= 1) am = fmaxf(am, __shfl_xor(am, m));
  const float sc = fmaxf(am / fmax, 1e-12f);
  const float q0 = fp8_round(v.x / sc, mbits, minnorm, subq);
  const float q1 = fp8_round(v.y / sc, mbits, minnorm, subq);
  uchar2 o;
  o.x = fp8_encode(q0, mbits, bias);
  o.y = fp8_encode(q1, mbits, bias);
  *(uchar2*)(q + base) = o;
  if (lane == 0) {
    const int kbs = 1 << kbshift;
    const int m = wid >> kbshift;
    const int kb = wid & (kbs - 1);
    sT[(size_t)kb * (nblk >> kbshift) + m] = sc;
  }
}

// weights are fp8-valued f32 -> exact byte encode
__global__ __launch_bounds__(256) void w_to_fp8_kernel(
    const float* __restrict__ in, uint8_t* __restrict__ out, int n4, int mbits, int bias) {
  const int i = blockIdx.x * 256 + threadIdx.x;
  if (i >= n4) return;
  float4 v = ((const float4*)in)[i];
  uchar4 o;
  o.x = fp8_encode(v.x, mbits, bias);
  o.y = fp8_encode(v.y, mbits, bias);
  o.z = fp8_encode(v.z, mbits, bias);
  o.w = fp8_encode(v.w, mbits, bias);
  *(uchar4*)(out + (size_t)i * 4) = o;
}

// concat 3 small scale vectors (n each) into o[0..3n)
__global__ void concat3_kernel(const float* __restrict__ a, const float* __restrict__ b,
                               const float* __restrict__ c, float* __restrict__ o, int n) {
  const int i = threadIdx.x;
  if (i < n) { o[i] = a[i]; o[n + i] = b[i]; o[2 * n + i] = c[i]; }
}

// f32 -> (hi bf16, lo bf16) compensated split, elementwise
__global__ __launch_bounds__(256) void split_bf16_kernel(
    const float* __restrict__ in, u16* __restrict__ hi, u16* __restrict__ lo, int n4) {
  const int i = blockIdx.x * 256 + threadIdx.x;
  if (i >= n4) return;
  float4 v = ((const float4*)in)[i];
  float f[4] = {v.x, v.y, v.z, v.w};
  ushort4 oh, ol;
  u16* ph = (u16*)&oh;
  u16* pl = (u16*)&ol;
#pragma unroll
  for (int j = 0; j < 4; ++j) {
    u16 h = bf16_rne(f[j]);
    float hf = __uint_as_float((uint32_t)h << 16);
    ph[j] = h;
    pl[j] = bf16_rne(f[j] - hf);
  }
  ((ushort4*)hi)[i] = oh;
  ((ushort4*)lo)[i] = ol;
}

// V [M=b*1024+t, 2048=h*128+d] f32 -> Vt hi/lo bf16 [bh][d][t]
__global__ __launch_bounds__(256) void vtrans_kernel(
    const float* __restrict__ v, u16* __restrict__ vth, u16* __restrict__ vtl) {
  __shared__ float tile[64][65];
  const int tid = threadIdx.x;
  const int t0 = blockIdx.x * 64;
  const int d0 = blockIdx.y * 64;
  const int bh = blockIdx.z;
  const int b = bh >> 4, h = bh & 15;
#pragma unroll
  for (int s = 0; s < 4; ++s) {
    const int e = s * 256 + tid;
    const int r = e >> 4, c4 = e & 15;
    float4 val = *(const float4*)(v + ((size_t)(b * 1024 + t0 + r)) * 2048 + h * 128 + d0 + c4 * 4);
    tile[r][c4 * 4 + 0] = val.x;
    tile[r][c4 * 4 + 1] = val.y;
    tile[r][c4 * 4 + 2] = val.z;
    tile[r][c4 * 4 + 3] = val.w;
  }
  __syncthreads();
#pragma unroll
  for (int s = 0; s < 4; ++s) {
    const int e = s * 256 + tid;
    const int dr = e >> 4, tc4 = e & 15;
    ushort4 oh, ol;
    u16* ph = (u16*)&oh;
    u16* pl = (u16*)&ol;
#pragma unroll
    for (int i = 0; i < 4; ++i) {
      float f = tile[tc4 * 4 + i][dr];
      u16 hv = bf16_rne(f);
      ph[i] = hv;
      pl[i] = bf16_rne(f - __uint_as_float((uint32_t)hv << 16));
    }
    const size_t ob = ((size_t)(bh * 128 + d0 + dr)) * 1024 + t0 + tc4 * 4;
    *(ushort4*)(vth + ob) = oh;
    *(ushort4*)(vtl + ob) = ol;
  }
}

// ---------------------------------------------------------------------------
// Wave-independent flash attention. Block = 32 Q rows; 4 waves split key
// tiles; barrier-free main loop; max-free softmax. (256,2): kernel needs
// ~184 unified VGPR+AGPR; tighter caps spill (r9). setprio kept (T5, m191).
// ---------------------------------------------------------------------------
__global__ __launch_bounds__(256, 2) void attn_wave_kernel(
    const float* __restrict__ Q, const u16* __restrict__ Kh, const u16* __restrict__ Kl,
    const u16* __restrict__ Vth, const u16* __restrict__ Vtl, float* __restrict__ Octx) {
  constexpr int PLD = 34;
  __shared__ uint32_t Psm[4][32 * PLD];
  __shared__ float Osum[32 * 128];
  __shared__ float lsh[4][32];

  const int tid = threadIdx.x;
  const int w = tid >> 6;
  const int lane = tid & 63;
  const int l31 = lane & 31;
  const int q2 = lane >> 5;
  const int bh = blockIdx.x;
  const int b = bh >> 4;
  const int hofs = (bh & 15) * 128;
  const int qt = 31 - (int)blockIdx.y;
  const int i0 = qt * 32;
  const float SC2 = 0.12752698f;  // log2(e)/sqrt(128)

  bf16x8 qh[8], ql[8];
  {
    const float* qp = Q + ((size_t)(b * 1024 + i0 + l31)) * 2048 + hofs + q2 * 8;
#pragma unroll
    for (int c = 0; c < 8; ++c) {
      float4 v0 = *(const float4*)(qp + c * 16);
      float4 v1 = *(const float4*)(qp + c * 16 + 4);
      float f[8] = {v0.x, v0.y, v0.z, v0.w, v1.x, v1.y, v1.z, v1.w};
      u16x8 uh, ul;
#pragma unroll
      for (int j = 0; j < 8; ++j) {
        u16 hv = bf16_rne(f[j]);
        uh[j] = hv;
        ul[j] = bf16_rne(f[j] - __uint_as_float((uint32_t)hv << 16));
      }
      qh[c] = __builtin_bit_cast(bf16x8, uh);
      ql[c] = __builtin_bit_cast(bf16x8, ul);
    }
  }

  const f32x16 z16 = {0.f};
  f32x16 Oacc[4] = {z16, z16, z16, z16};
  float lr[16];
#pragma unroll
  for (int r = 0; r < 16; ++r) lr[r] = 0.f;
  int rowq[16];
#pragma unroll
  for (int r = 0; r < 16; ++r) rowq[r] = (r & 3) + 8 * (r >> 2) + 4 * q2;

  uint32_t* Pw = Psm[w];
  for (int kt = w; kt <= qt; kt += 4) {
    const int j0 = kt * 32;
    const size_t krow = ((size_t)(b * 1024 + j0 + l31)) * 2048 + hofs + q2 * 8;
    f32x16 S = z16;
#pragma unroll
    for (int c = 0; c < 8; ++c) {
      bf16x8 k8h = *(const bf16x8*)(Kh + krow + c * 16);
      bf16x8 k8l = *(const bf16x8*)(Kl + krow + c * 16);
      __builtin_amdgcn_s_setprio(1);
      S = __builtin_amdgcn_mfma_f32_32x32x16_bf16(qh[c], k8h, S, 0, 0, 0);
      S = __builtin_amdgcn_mfma_f32_32x32x16_bf16(qh[c], k8l, S, 0, 0, 0);
      S = __builtin_amdgcn_mfma_f32_32x32x16_bf16(ql[c], k8h, S, 0, 0, 0);
      __builtin_amdgcn_s_setprio(0);
    }
    if (kt == qt) {
#pragma unroll
      for (int r = 0; r < 16; ++r)
        if (l31 > rowq[r]) S[r] = -3e38f;
    }
#pragma unroll
    for (int r = 0; r < 16; ++r) {
      const float p = EXP2F(S[r] * SC2);
      lr[r] += p;
      const u16 ph = bf16_rne(p);
      const u16 pl = bf16_rne(p - __uint_as_float((uint32_t)ph << 16));
      Pw[rowq[r] * PLD + l31] = (uint32_t)ph | ((uint32_t)pl << 16);
    }
#pragma unroll
    for (int s = 0; s < 2; ++s) {
      const uint32_t* rp = Pw + l31 * PLD + s * 16 + q2 * 8;
      uint2 a0 = *(const uint2*)(rp + 0);
      uint2 a1 = *(const uint2*)(rp + 2);
      uint2 a2 = *(const uint2*)(rp + 4);
      uint2 a3 = *(const uint2*)(rp + 6);
      u16x8 uh, ul;
      uh[0] = (u16)a0.x; ul[0] = (u16)(a0.x >> 16);
      uh[1] = (u16)a0.y; ul[1] = (u16)(a0.y >> 16);
      uh[2] = (u16)a1.x; ul[2] = (u16)(a1.x >> 16);
      uh[3] = (u16)a1.y; ul[3] = (u16)(a1.y >> 16);
      uh[4] = (u16)a2.x; ul[4] = (u16)(a2.x >> 16);
      uh[5] = (u16)a2.y; ul[5] = (u16)(a2.y >> 16);
      uh[6] = (u16)a3.x; ul[6] = (u16)(a3.x >> 16);
      uh[7] = (u16)a3.y; ul[7] = (u16)(a3.y >> 16);
      bf16x8 p8h = __builtin_bit_cast(bf16x8, uh);
      bf16x8 p8l = __builtin_bit_cast(bf16x8, ul);
      const size_t vrow = ((size_t)(bh * 128 + l31)) * 1024 + j0 + s * 16 + q2 * 8;
#pragma unroll
      for (int dt = 0; dt < 4; ++dt) {
        bf16x8 v8h = *(const bf16x8*)(Vth + vrow + (size_t)dt * 32768);
        bf16x8 v8l = *(const bf16x8*)(Vtl + vrow + (size_t)dt * 32768);
        __builtin_amdgcn_s_setprio(1);
        Oacc[dt] = __builtin_amdgcn_mfma_f32_32x32x16_bf16(p8h, v8h, Oacc[dt], 0, 0, 0);
        Oacc[dt] = __builtin_amdgcn_mfma_f32_32x32x16_bf16(p8h, v8l, Oacc[dt], 0, 0, 0);
        Oacc[dt] = __builtin_amdgcn_mfma_f32_32x32x16_bf16(p8l, v8h, Oacc[dt], 0, 0, 0);
        __builtin_amdgcn_s_setprio(0);
      }
    }
  }

#pragma unroll
  for (int r = 0; r < 16; ++r) {
    float t = lr[r];
    t += __shfl_xor(t, 1);
    t += __shfl_xor(t, 2);
    t += __shfl_xor(t, 4);
    t += __shfl_xor(t, 8);
    t += __shfl_xor(t, 16);
    lr[r] = t;
  }
  if (l31 == 0) {
#pragma unroll
    for (int r = 0; r < 16; ++r) lsh[w][rowq[r]] = lr[r];
  }
  if (w == 0) {
#pragma unroll
    for (int dt = 0; dt < 4; ++dt)
#pragma unroll
      for (int r = 0; r < 16; ++r) Osum[rowq[r] * 128 + dt * 32 + l31] = Oacc[dt][r];
  }
  __syncthreads();
  if (w == 1) {
#pragma unroll
    for (int dt = 0; dt < 4; ++dt)
#pragma unroll
      for (int r = 0; r < 16; ++r) Osum[rowq[r] * 128 + dt * 32 + l31] += Oacc[dt][r];
  }
  __syncthreads();
  if (w == 2) {
#pragma unroll
    for (int dt = 0; dt < 4; ++dt)
#pragma unroll
      for (int r = 0; r < 16; ++r) Osum[rowq[r] * 128 + dt * 32 + l31] += Oacc[dt][r];
  }
  __syncthreads();
  if (w == 3) {
#pragma unroll
    for (int dt = 0; dt < 4; ++dt)
#pragma unroll
      for (int r = 0; r < 16; ++r) Osum[rowq[r] * 128 + dt * 32 + l31] += Oacc[dt][r];
  }
  __syncthreads();
  const int row = w * 8 + (lane >> 3);
  const int c0 = (lane & 7) * 16;
  const float inv = 1.0f / (lsh[0][row] + lsh[1][row] + lsh[2][row] + lsh[3][row]);
  float* op = Octx + ((size_t)(b * 1024 + i0 + row)) * 2048 + hofs + c0;
#pragma unroll
  for (int i2 = 0; i2 < 4; ++i2) {
    float4 v = *(const float4*)(Osum + row * 128 + c0 + i2 * 4);
    v.x *= inv; v.y *= inv; v.z *= inv; v.w *= inv;
    *(float4*)(op + i2 * 4) = v;
  }
}

// ---------------------------------------------------------------------------
// Unified MX-fp8 GEMM: 128x128 tile, BK=64, double-buffered counted-vmcnt
// pipeline. LDS = 2x(8KB A + 8KB W) + NK*512B scale slab = 40KB (K=2048,
// 4 blocks/CU) / 64KB (K=8192, 2 blocks/CU). Per K-step per wave: 4
// global_load_lds stage of step t+2, 8 ds_read_b128, 4 mfma_scale_32x32x64,
// 64-FMA fold from LDS slab; s_waitcnt vmcnt(4) — never 0 mid-loop, so one
// tile is always in flight while TLP (4 blocks/CU) covers the rest.
// Fold per 64-K step (vs per-128 before): few-ULP reassociation, keeps chk
// lifetime within a step so VGPR stays <=128 (occupancy!).
// XOR swizzle at 16B granularity: LDS chunk p of row r holds global chunk
// p^(r&3); staging pre-swizzles the per-lane GLOBAL address (dest stays
// linear, rule #21). FMT: 0 = e4m3fn, 1 = e5m2.
// C[m,n] = wsc[n>>7]*sum_kb sxT[kb][m]*sum_k A[m,k]W[n,k] (+bias,+gelu).
// ---------------------------------------------------------------------------
template <int FMT, int NK>
__global__ __launch_bounds__(256, 2) void gemm_db(
    const uint8_t* __restrict__ A, const float* __restrict__ sxT,
    const uint8_t* __restrict__ W, const float* __restrict__ wsc,
    const float* __restrict__ bias, float* __restrict__ out,
    int M, int N, int K, int gelu, int seg_shift, int Nw) {
  __shared__ uint8_t As[2][128 * 64];
  __shared__ uint8_t Ws[2][128 * 64];
  __shared__ float sxs[NK * 128];  // activation scales for this bm slab

  const int tid = threadIdx.x;
  const int lane = tid & 63;
  const int wave = tid >> 6;
  const int wm = (wave >> 1) * 64;
  const int wn = (wave & 1) * 64;
  const int l31 = lane & 31;
  const int q2 = lane >> 5;
  const int bm = blockIdx.y * 128;
  const int bn = blockIdx.x * 128;

  // prologue: sxT slab -> LDS  (sxs[kt*128 + r] = sxT[kt*M + bm + r])
#pragma unroll
  for (int t = 0; t < NK * 128 / 1024; ++t) {
    const int e = t * 1024 + tid * 4;
    const int kt = e >> 7, r = e & 127;
    *(float4*)(sxs + e) = *(const float4*)(sxT + (size_t)kt * M + bm + r);
  }
  // drain slab staging completely so steady-state vmcnt counting is exact
  asm volatile("s_waitcnt vmcnt(0) lgkmcnt(0)" ::: "memory");
  __builtin_amdgcn_s_barrier();
  CFENCE();

  // staging (BK=64): wave w stages rows [w*32, w*32+32) via 2 instrs of 16
  // rows x 64B. Lane covers row w*32 + s*16 + (lane>>2), LDS chunk lane&3;
  // global chunk = (lane&3)^(row&3) (row&3 == (lane>>2)&3, s-independent).
  const int srow = wave * 32 + (lane >> 2);
  const int gchunk = (lane & 3) ^ ((lane >> 2) & 3);
  const uint8_t* ga = A + (size_t)(bm + srow) * K + gchunk * 16;
  const uint8_t* gw = W + (size_t)(bn + srow) * K + gchunk * 16;
  const int lofs = wave * 2048 + lane * 16;

  const f32x16 z16 = {0.f};
  f32x16 acc[2][2] = {{z16, z16}, {z16, z16}};

  // prologue staging: step0 -> buf0, step1 -> buf1 (8 gl_lds outstanding)
#pragma unroll
  for (int s = 0; s < 2; ++s) {
    gl_lds16(ga + (size_t)s * 16 * K, &As[0][lofs + s * 1024]);
    gl_lds16(gw + (size_t)s * 16 * K, &Ws[0][lofs + s * 1024]);
  }
  ga += 64;
  gw += 64;
#pragma unroll
  for (int s = 0; s < 2; ++s) {
    gl_lds16(ga + (size_t)s * 16 * K, &As[1][lofs + s * 1024]);
    gl_lds16(gw + (size_t)s * 16 * K, &Ws[1][lofs + s * 1024]);
  }
  ga += 64;
  gw += 64;
  // step0's 4 loads done (oldest of 8); step1's stay in flight
  asm volatile("s_waitcnt vmcnt(4)" ::: "memory");
  __builtin_amdgcn_s_barrier();
  CFENCE();

  const int NK2 = NK * 2;  // number of 64-K steps
  for (int t = 0; t < NK2; ++t) {
    const uint8_t* Asc = As[t & 1];
    const uint8_t* Wsc = Ws[t & 1];
    // ---- compute step t (LDS + MFMA + fold; no VMEM) ----
    i32x8 af[2], bf2[2];
    const int c0 = q2 * 2;  // lane's first 16B chunk within the 64B row
#pragma unroll
    for (int i = 0; i < 2; ++i) {
      const int r = wm + i * 32 + l31;
      const uint8_t* Ar = Asc + r * 64;
      const int s3 = r & 3;
      af[i] = pack8(*(const uint4*)(Ar + ((c0 ^ s3) * 16)),
                    *(const uint4*)(Ar + (((c0 + 1) ^ s3) * 16)));
    }
#pragma unroll
    for (int j = 0; j < 2; ++j) {
      const int r = wn + j * 32 + l31;
      const uint8_t* Wr = Wsc + r * 64;
      const int s3 = r & 3;
      bf2[j] = pack8(*(const uint4*)(Wr + ((c0 ^ s3) * 16)),
                     *(const uint4*)(Wr + (((c0 + 1) ^ s3) * 16)));
    }
    f32x16 chk[2][2];
#pragma unroll
    for (int i = 0; i < 2; ++i)
#pragma unroll
      for (int j = 0; j < 2; ++j)
        chk[i][j] = __builtin_amdgcn_mfma_scale_f32_32x32x64_f8f6f4(
            af[i], bf2[j], z16, FMT, FMT, 0, 0x7F7F7F7F, 0, 0x7F7F7F7F);
    // fold this step's contribution with the 128-K block's activation scale
    const float* svl = sxs + (t >> 1) * 128 + wm + q2 * 4;
#pragma unroll
    for (int i = 0; i < 2; ++i) {
#pragma unroll
      for (int rg = 0; rg < 4; ++rg) {
        const f32x4 sv = *(const f32x4*)(svl + i * 32 + rg * 8);
#pragma unroll
        for (int j = 0; j < 2; ++j)
#pragma unroll
          for (int rr = 0; rr < 4; ++rr)
            acc[i][j][rg * 4 + rr] += sv[rr] * chk[i][j][rg * 4 + rr];
      }
    }
    // ---- pipeline boundary ----
    CFENCE();
    __builtin_amdgcn_s_barrier();  // all waves done reading buf[t&1]
    CFENCE();
    if (t + 1 < NK2) {
      if (t + 2 < NK2) {
        uint8_t* Asn = &As[t & 1][lofs];  // just-freed buffer
        uint8_t* Wsn = &Ws[t & 1][lofs];
#pragma unroll
        for (int s = 0; s < 2; ++s) {
          gl_lds16(ga + (size_t)s * 16 * K, Asn + s * 1024);
          gl_lds16(gw + (size_t)s * 16 * K, Wsn + s * 1024);
        }
        ga += 64;
        gw += 64;
        // step t+1's loads done; step t+2's stay in flight
        asm volatile("s_waitcnt vmcnt(4)" ::: "memory");
      } else {
        asm volatile("s_waitcnt vmcnt(0)" ::: "memory");  // last step landed
      }
      __builtin_amdgcn_s_barrier();  // buf[(t+1)&1] ready for all waves
      CFENCE();
    }
  }

#pragma unroll
  for (int i = 0; i < 2; ++i) {
#pragma unroll
    for (int j = 0; j < 2; ++j) {
      const int n = bn + wn + j * 32 + l31;
      const float wsn = wsc[n >> 7];
      const float bv = bias ? bias[n] : 0.f;
      const int seg = n >> seg_shift;
      const int col = n & ((1 << seg_shift) - 1);
      float* op = out + (size_t)seg * M * Nw + col;
#pragma unroll
      for (int reg = 0; reg < 16; ++reg) {
        const int m = bm + wm + i * 32 + (reg & 3) + 8 * (reg >> 2) + 4 * q2;
        float v = acc[i][j][reg] * wsn + bv;
        if (gelu) v = 0.5f * v * (1.f + erff(v * 0.70710678118654752440f));
        op[(size_t)m * Nw] = v;
      }
    }
  }
}

// out = LN(a + b) * (g*gs_rep) + (bb*bs_rep), eps=1e-5, C=2048, one block/row
__global__ __launch_bounds__(256) void ln_kernel(
    const float* __restrict__ a, const float* __restrict__ b2,
    const float* __restrict__ g, const float* __restrict__ gs,
    const float* __restrict__ bb, const float* __restrict__ bs,
    float* __restrict__ out, int C) {
  __shared__ float red[4];
  const int tid = threadIdx.x;
  const int row = blockIdx.x;
  const float* pa = a + (size_t)row * C;
  const float* pb = b2 + (size_t)row * C;
  float v[8];
  float sum = 0.f;
#pragma unroll
  for (int k = 0; k < 8; ++k) {
    const int c = tid + (k << 8);
    v[k] = pa[c] + pb[c];
    sum += v[k];
  }
#pragma unroll
  for (int m = 32; m >= 1; m >>= 1) sum += __shfl_xor(sum, m);
  if ((tid & 63) == 0) red[tid >> 6] = sum;
  __syncthreads();
  const float mean = (red[0] + red[1] + red[2] + red[3]) * (1.f / 2048.f);
  __syncthreads();
  float sq = 0.f;
#pragma unroll
  for (int k = 0; k < 8; ++k) {
    const float d = v[k] - mean;
    sq += d * d;
  }
#pragma unroll
  for (int m = 32; m >= 1; m >>= 1) sq += __shfl_xor(sq, m);
  if ((tid & 63) == 0) red[tid >> 6] = sq;
  __syncthreads();
  const float var = (red[0] + red[1] + red[2] + red[3]) * (1.f / 2048.f);
  const float inv = 1.0f / sqrtf(var + 1e-5f);
  float* po = out + (size_t)row * C;
#pragma unroll
  for (int k = 0; k < 8; ++k) {
    const int c = tid + (k << 8);
    po[c] = (v[k] - mean) * inv * (g[c] * gs[c >> 7]) + bb[c] * bs[c >> 7];
  }
}

extern "C" void kernel_launch(void* const* d_in, const int* in_sizes, int n_in,
                              void* d_out, int out_size, void* d_ws, size_t ws_size,
                              hipStream_t stream) {
  const int C = 2048, MLP = 8192;
  const int M = 2048;  // B*T tokens

  const float* x = (const float*)d_in[0];
  const float* wq = (const float*)d_in[2];
  const float* qs = (const float*)d_in[3];
  const float* wk = (const float*)d_in[4];
  const float* ks = (const float*)d_in[5];
  const float* wv = (const float*)d_in[6];
  const float* vs = (const float*)d_in[7];
  const float* wo = (const float*)d_in[8];
  const float* os_ = (const float*)d_in[9];
  const float* fc1_w = (const float*)d_in[10];
  const float* fc1_s = (const float*)d_in[11];
  const float* fc1_b = (const float*)d_in[12];
  const float* fc2_w = (const float*)d_in[13];
  const float* fc2_s = (const float*)d_in[14];
  const float* fc2_b = (const float*)d_in[15];
  const float* ln1_g = (const float*)d_in[16];
  const float* ln1_gs = (const float*)d_in[17];
  const float* ln1_b = (const float*)d_in[18];
  const float* ln1_bs = (const float*)d_in[19];
  const float* ln2_g = (const float*)d_in[20];
  const float* ln2_gs = (const float*)d_in[21];
  const float* ln2_b = (const float*)d_in[22];
  const float* ln2_bs = (const float*)d_in[23];

  char* ws = (char*)d_ws;
  const size_t o_Aq = 0;           // 32 MB; aliased by Kh/Kl/Vth/Vtl during attention
  const size_t o_Wb = 33554432;    // 32 MB fp8 weights
  const size_t o_sx = 67108864;    // 512 KB activation scales (transposed)
  const size_t o_ln1 = 67633152;   // 16 MB
  const size_t o_q = 84410368;     // 16 MB
  const size_t o_k = 101187584;    // 16 MB (contiguous after o_q)
  const size_t o_v = 117964800;    // 16 MB (contiguous after o_k)
  const size_t o_ctx = 134742016;  // 16 MB
  const size_t o_attn = 151519232; // 16 MB -> end 168296448
  const size_t o_h = o_q;          // 64 MB over q..ctx (dead by then)
  const size_t o_ffn = o_attn;
  if (ws_size < 168296448ull) return;

  uint8_t* Aq = (uint8_t*)(ws + o_Aq);
  uint8_t* Wb = (uint8_t*)(ws + o_Wb);
  float* sx = (float*)(ws + o_sx);
  float* wsc3 = (float*)(ws + o_sx + 262144);  // dead part of sx region during qkv
  float* ln1o = (float*)(ws + o_ln1);
  float* qb = (float*)(ws + o_q);
  float* kb = (float*)(ws + o_k);
  float* vb = (float*)(ws + o_v);
  float* ctx = (float*)(ws + o_ctx);
  float* attn_out = (float*)(ws + o_attn);
  float* hb = (float*)(ws + o_h);
  float* ffn = (float*)(ws + o_ffn);
  float* outp = (float*)d_out;
  // attention splits alias the (dead between gemm_qkv and qdq(ctx)) Aq region
  u16* Kh = (u16*)(ws + o_Aq);
  u16* Kl = (u16*)(ws + o_Aq + 8388608);
  u16* Vth = (u16*)(ws + o_Aq + 16777216);
  u16* Vtl = (u16*)(ws + o_Aq + 25165824);

  const float E5_MAX = 57344.f, E5_MINN = 6.103515625e-05f, E5_SUBQ = 1.52587890625e-05f;
  const float E4_MAX = 448.f, E4_MINN = 0.015625f, E4_SUBQ = 0.001953125f;

  const dim3 blk(256);
  const int wc_qkv = (C * C / 4 + 255) / 256;
  const int wc_fc = (C * MLP / 4 + 255) / 256;

  // ---- fused qkv projection (e5m2 = fmt 1): one GEMM (N=6144) ----
  qdq_kernel<<<M * (C / 128) / 4, blk, 0, stream>>>(x, Aq, sx, M * (C / 128), 4, E5_MAX, E5_MINN, E5_SUBQ, 2, 15);
  w_to_fp8_kernel<<<wc_qkv, blk, 0, stream>>>(wq, Wb, C * C / 4, 2, 15);
  w_to_fp8_kernel<<<wc_qkv, blk, 0, stream>>>(wk, Wb + C * C, C * C / 4, 2, 15);
  w_to_fp8_kernel<<<wc_qkv, blk, 0, stream>>>(wv, Wb + 2 * C * C, C * C / 4, 2, 15);
  concat3_kernel<<<1, 64, 0, stream>>>(qs, ks, vs, wsc3, C / 128);
  gemm_db<1, 16><<<dim3(3 * C / 128, M / 128), blk, 0, stream>>>(
      Aq, sx, Wb, wsc3, nullptr, qb, M, 3 * C, C, 0, 11, C);

  // ---- attention (bf16x3 MFMA flash, wave-independent) ----
  split_bf16_kernel<<<(M * C / 4 + 255) / 256, blk, 0, stream>>>(kb, Kh, Kl, M * C / 4);
  vtrans_kernel<<<dim3(16, 2, 32), blk, 0, stream>>>(vb, Vth, Vtl);
  attn_wave_kernel<<<dim3(32, 32), blk, 0, stream>>>(qb, Kh, Kl, Vth, Vtl, ctx);

  // ---- attn-out projection ----
  qdq_kernel<<<M * (C / 128) / 4, blk, 0, stream>>>(ctx, Aq, sx, M * (C / 128), 4, E5_MAX, E5_MINN, E5_SUBQ, 2, 15);
  w_to_fp8_kernel<<<wc_qkv, blk, 0, stream>>>(wo, Wb, C * C / 4, 2, 15);
  gemm_db<1, 16><<<dim3(C / 128, M / 128), blk, 0, stream>>>(
      Aq, sx, Wb, os_, nullptr, attn_out, M, C, C, 0, 30, C);

  ln_kernel<<<M, blk, 0, stream>>>(x, attn_out, ln1_g, ln1_gs, ln1_b, ln1_bs, ln1o, C);

  // ---- MLP (e4m3fn = fmt 0) ----
  qdq_kernel<<<M * (C / 128) / 4, blk, 0, stream>>>(ln1o, Aq, sx, M * (C / 128), 4, E4_MAX, E4_MINN, E4_SUBQ, 3, 7);
  w_to_fp8_kernel<<<wc_fc, blk, 0, stream>>>(fc1_w, Wb, C * MLP / 4, 3, 7);
  gemm_db<0, 16><<<dim3(MLP / 128, M / 128), blk, 0, stream>>>(
      Aq, sx, Wb, fc1_s, fc1_b, hb, M, MLP, C, 1, 30, MLP);

  qdq_kernel<<<M * (MLP / 128) / 4, blk, 0, stream>>>(hb, Aq, sx, M * (MLP / 128), 6, E4_MAX, E4_MINN, E4_SUBQ, 3, 7);
  w_to_fp8_kernel<<<wc_fc, blk, 0, stream>>>(fc2_w, Wb, C * MLP / 4, 3, 7);
  gemm_db<0, 64><<<dim3(C / 128, M / 128), blk, 0, stream>>>(
      Aq, sx, Wb, fc2_s, fc2_b, ffn, M, C, MLP, 0, 30, C);

  ln_kernel<<<M, blk, 0, stream>>>(ln1o, ffn, ln2_g, ln2_gs, ln2_b, ln2_bs, outp, C);
}

// Round 8
// 657.156 us; speedup vs baseline: 1.0578x; 1.0578x over previous
//
#include <hip/hip_runtime.h>
#include <cstdint>

// ---------------------------------------------------------------------------
// FP8TransformerLayer on MI355X (gfx950) — round 12: producer-side qdq fusion.
// 7 rounds of GEMM-structure work all landed 654-695us: the 128^2 MX-fp8 GEMM
// is at its shape-adjusted ceiling (~530-650 TF vs m102-scaled ~570-810).
// The remaining fat is the f32->qdq round-trips: fc1 wrote 64MB hb then qdq
// re-read it; attn wrote 16MB ctx then qdq re-read; ln1 output re-read.
// Quant blocks (128 wide) align with tile/head/row boundaries everywhere, so
// quantization fuses into each producer's epilogue (exact max + identical
// encode math -> bit-identical, absmax 0.05273438). GEMMs are the r0-proven
// all-simple structure; attention r10 (256,2)+setprio. 3 qdq dispatches and
// 2 w_to_fp8 launches removed; ~180MB HBM traffic cut.
// B=2 T=1024 C=2048 H=16 HD=128 MLP=8192, BS=128 quant blocks.
// ---------------------------------------------------------------------------

typedef __bf16 bf16x8 __attribute__((ext_vector_type(8)));
typedef unsigned short u16x8 __attribute__((ext_vector_type(8)));
typedef float f32x4 __attribute__((ext_vector_type(4)));
typedef float f32x16 __attribute__((ext_vector_type(16)));
typedef int i32x8 __attribute__((ext_vector_type(8)));
typedef unsigned short u16;

#if __has_builtin(__builtin_amdgcn_exp2f)
#define EXP2F(x) __builtin_amdgcn_exp2f(x)
#else
#define EXP2F(x) exp2f(x)
#endif

__device__ __forceinline__ void gl_lds16(const void* g, void* l) {
  __builtin_amdgcn_global_load_lds(
      (const __attribute__((address_space(1))) void*)g,
      (__attribute__((address_space(3))) void*)l, 16, 0, 0);
}

struct u4x2 { uint4 a, b; };
__device__ __forceinline__ i32x8 pack8(uint4 lo, uint4 hi) {
  u4x2 t{lo, hi};
  return __builtin_bit_cast(i32x8, t);
}

__device__ __forceinline__ u16 bf16_rne(float v) {
  uint32_t u = __float_as_uint(v);
  u += 0x7FFFu + ((u >> 16) & 1u);
  return (u16)(u >> 16);
}

__device__ __forceinline__ float fp8_round(float v, int mbits, float minnorm, float subq) {
  float av = fabsf(v);
  if (av < minnorm) {
    return rintf(v / subq) * subq;  // subnormal grid, RNE
  }
  uint32_t u = __float_as_uint(v);
  const int shift = 23 - mbits;
  const uint32_t mask = (1u << shift) - 1u;
  const uint32_t rem = u & mask;
  uint32_t base = u & ~mask;
  const uint32_t half = 1u << (shift - 1);
  if (rem > half || (rem == half && ((base >> shift) & 1u))) base += (1u << shift);
  return __uint_as_float(base);
}

// exact byte encode of an fp8-representable f32 (e4m3fn: mbits=3,bias=7;
// e5m2: mbits=2,bias=15)
__device__ __forceinline__ uint8_t fp8_encode(float v, int mbits, int bias) {
  uint32_t u = __float_as_uint(v);
  uint32_t sign = (u >> 31) << 7;
  if ((u & 0x7FFFFFFFu) == 0) return (uint8_t)sign;
  int e = (int)((u >> 23) & 255u) - 127;
  if (e >= 1 - bias) {
    uint32_t mant = (u >> (23 - mbits)) & ((1u << mbits) - 1u);
    return (uint8_t)(sign | ((uint32_t)(e + bias) << mbits) | mant);
  }
  // subnormal: |v| * 2^(bias-1+mbits) is an exact small integer
  float q = fabsf(v) * __uint_as_float((uint32_t)(127 + bias - 1 + mbits) << 23);
  return (uint8_t)(sign | (uint32_t)q);
}

// quantize one value with E5M2 / E4M3 constants
__device__ __forceinline__ uint8_t q_e5(float v, float sc) {
  return fp8_encode(fp8_round(v / sc, 2, 6.103515625e-05f, 1.52587890625e-05f), 2, 15);
}
__device__ __forceinline__ uint8_t q_e4(float v, float sc) {
  return fp8_encode(fp8_round(v / sc, 3, 0.015625f, 0.001953125f), 3, 7);
}

// one 64-lane wave per 128-element quant block; fp8 BYTES out; scale written
// TRANSPOSED: sT[kb * Mtot + m], kb = wid & (kbs-1), m = wid >> kbshift.
__global__ __launch_bounds__(256) void qdq_kernel(
    const float* __restrict__ x, uint8_t* __restrict__ q, float* __restrict__ sT,
    int nblk, int kbshift, float fmax, float minnorm, float subq, int mbits, int bias) {
  const int wid = blockIdx.x * 4 + (threadIdx.x >> 6);
  if (wid >= nblk) return;
  const int lane = threadIdx.x & 63;
  const size_t base = (size_t)wid * 128 + (size_t)lane * 2;
  float2 v = *(const float2*)(x + base);
  float am = fmaxf(fabsf(v.x), fabsf(v.y));
#pragma unroll
  for (int m = 32; m >= 1; m >>= 1) am = fmaxf(am, __shfl_xor(am, m));
  const float sc = fmaxf(am / fmax, 1e-12f);
  const float q0 = fp8_round(v.x / sc, mbits, minnorm, subq);
  const float q1 = fp8_round(v.y / sc, mbits, minnorm, subq);
  uchar2 o;
  o.x = fp8_encode(q0, mbits, bias);
  o.y = fp8_encode(q1, mbits, bias);
  *(uchar2*)(q + base) = o;
  if (lane == 0) {
    const int kbs = 1 << kbshift;
    const int m = wid >> kbshift;
    const int kb = wid & (kbs - 1);
    sT[(size_t)kb * (nblk >> kbshift) + m] = sc;
  }
}

// weights are fp8-valued f32 -> exact byte encode
__global__ __launch_bounds__(256) void w_to_fp8_kernel(
    const float* __restrict__ in, uint8_t* __restrict__ out, int n4, int mbits, int bias) {
  const int i = blockIdx.x * 256 + threadIdx.x;
  if (i >= n4) return;
  float4 v = ((const float4*)in)[i];
  uchar4 o;
  o.x = fp8_encode(v.x, mbits, bias);
  o.y = fp8_encode(v.y, mbits, bias);
  o.z = fp8_encode(v.z, mbits, bias);
  o.w = fp8_encode(v.w, mbits, bias);
  *(uchar4*)(out + (size_t)i * 4) = o;
}

// 3 same-size weights -> fp8 bytes in one dispatch (e5m2)
__global__ __launch_bounds__(256) void w3_to_fp8_kernel(
    const float* __restrict__ a, const float* __restrict__ b,
    const float* __restrict__ c, uint8_t* __restrict__ out, int n4) {
  const int i = blockIdx.x * 256 + threadIdx.x;
  if (i >= n4) return;
  const float* in = blockIdx.y == 0 ? a : (blockIdx.y == 1 ? b : c);
  float4 v = ((const float4*)in)[i];
  uchar4 o;
  o.x = fp8_encode(v.x, 2, 15);
  o.y = fp8_encode(v.y, 2, 15);
  o.z = fp8_encode(v.z, 2, 15);
  o.w = fp8_encode(v.w, 2, 15);
  *(uchar4*)(out + (size_t)blockIdx.y * n4 * 4 + (size_t)i * 4) = o;
}

// concat 3 small scale vectors (n each) into o[0..3n)
__global__ void concat3_kernel(const float* __restrict__ a, const float* __restrict__ b,
                               const float* __restrict__ c, float* __restrict__ o, int n) {
  const int i = threadIdx.x;
  if (i < n) { o[i] = a[i]; o[n + i] = b[i]; o[2 * n + i] = c[i]; }
}

// f32 -> (hi bf16, lo bf16) compensated split, elementwise
__global__ __launch_bounds__(256) void split_bf16_kernel(
    const float* __restrict__ in, u16* __restrict__ hi, u16* __restrict__ lo, int n4) {
  const int i = blockIdx.x * 256 + threadIdx.x;
  if (i >= n4) return;
  float4 v = ((const float4*)in)[i];
  float f[4] = {v.x, v.y, v.z, v.w};
  ushort4 oh, ol;
  u16* ph = (u16*)&oh;
  u16* pl = (u16*)&ol;
#pragma unroll
  for (int j = 0; j < 4; ++j) {
    u16 h = bf16_rne(f[j]);
    float hf = __uint_as_float((uint32_t)h << 16);
    ph[j] = h;
    pl[j] = bf16_rne(f[j] - hf);
  }
  ((ushort4*)hi)[i] = oh;
  ((ushort4*)lo)[i] = ol;
}

// V [M=b*1024+t, 2048=h*128+d] f32 -> Vt hi/lo bf16 [bh][d][t]
__global__ __launch_bounds__(256) void vtrans_kernel(
    const float* __restrict__ v, u16* __restrict__ vth, u16* __restrict__ vtl) {
  __shared__ float tile[64][65];
  const int tid = threadIdx.x;
  const int t0 = blockIdx.x * 64;
  const int d0 = blockIdx.y * 64;
  const int bh = blockIdx.z;
  const int b = bh >> 4, h = bh & 15;
#pragma unroll
  for (int s = 0; s < 4; ++s) {
    const int e = s * 256 + tid;
    const int r = e >> 4, c4 = e & 15;
    float4 val = *(const float4*)(v + ((size_t)(b * 1024 + t0 + r)) * 2048 + h * 128 + d0 + c4 * 4);
    tile[r][c4 * 4 + 0] = val.x;
    tile[r][c4 * 4 + 1] = val.y;
    tile[r][c4 * 4 + 2] = val.z;
    tile[r][c4 * 4 + 3] = val.w;
  }
  __syncthreads();
#pragma unroll
  for (int s = 0; s < 4; ++s) {
    const int e = s * 256 + tid;
    const int dr = e >> 4, tc4 = e & 15;
    ushort4 oh, ol;
    u16* ph = (u16*)&oh;
    u16* pl = (u16*)&ol;
#pragma unroll
    for (int i = 0; i < 4; ++i) {
      float f = tile[tc4 * 4 + i][dr];
      u16 hv = bf16_rne(f);
      ph[i] = hv;
      pl[i] = bf16_rne(f - __uint_as_float((uint32_t)hv << 16));
    }
    const size_t ob = ((size_t)(bh * 128 + d0 + dr)) * 1024 + t0 + tc4 * 4;
    *(ushort4*)(vth + ob) = oh;
    *(ushort4*)(vtl + ob) = ol;
  }
}

// ---------------------------------------------------------------------------
// Wave-independent flash attention, FUSED qdq epilogue: each block holds 32
// rows x 128 dims (one head) of the f32 context in Osum — exactly one quant
// block per row — so it quantizes in-register (8-lane shfl max, identical
// encode math as qdq_kernel -> bit-identical) and writes fp8 bytes + scales
// directly. The 16MB f32 ctx buffer and the qdq(ctx) dispatch disappear.
// (256,2): ~184 unified VGPR+AGPR demand; tighter caps spill (r9 lesson).
// ---------------------------------------------------------------------------
__global__ __launch_bounds__(256, 2) void attn_wave_kernel(
    const float* __restrict__ Q, const u16* __restrict__ Kh, const u16* __restrict__ Kl,
    const u16* __restrict__ Vth, const u16* __restrict__ Vtl,
    uint8_t* __restrict__ Aqo, float* __restrict__ sTo) {
  constexpr int PLD = 34;
  __shared__ uint32_t Psm[4][32 * PLD];
  __shared__ float Osum[32 * 128];
  __shared__ float lsh[4][32];

  const int tid = threadIdx.x;
  const int w = tid >> 6;
  const int lane = tid & 63;
  const int l31 = lane & 31;
  const int q2 = lane >> 5;
  const int bh = blockIdx.x;
  const int b = bh >> 4;
  const int hofs = (bh & 15) * 128;
  const int qt = 31 - (int)blockIdx.y;
  const int i0 = qt * 32;
  const float SC2 = 0.12752698f;  // log2(e)/sqrt(128)

  bf16x8 qh[8], ql[8];
  {
    const float* qp = Q + ((size_t)(b * 1024 + i0 + l31)) * 2048 + hofs + q2 * 8;
#pragma unroll
    for (int c = 0; c < 8; ++c) {
      float4 v0 = *(const float4*)(qp + c * 16);
      float4 v1 = *(const float4*)(qp + c * 16 + 4);
      float f[8] = {v0.x, v0.y, v0.z, v0.w, v1.x, v1.y, v1.z, v1.w};
      u16x8 uh, ul;
#pragma unroll
      for (int j = 0; j < 8; ++j) {
        u16 hv = bf16_rne(f[j]);
        uh[j] = hv;
        ul[j] = bf16_rne(f[j] - __uint_as_float((uint32_t)hv << 16));
      }
      qh[c] = __builtin_bit_cast(bf16x8, uh);
      ql[c] = __builtin_bit_cast(bf16x8, ul);
    }
  }

  const f32x16 z16 = {0.f};
  f32x16 Oacc[4] = {z16, z16, z16, z16};
  float lr[16];
#pragma unroll
  for (int r = 0; r < 16; ++r) lr[r] = 0.f;
  int rowq[16];
#pragma unroll
  for (int r = 0; r < 16; ++r) rowq[r] = (r & 3) + 8 * (r >> 2) + 4 * q2;

  uint32_t* Pw = Psm[w];
  for (int kt = w; kt <= qt; kt += 4) {
    const int j0 = kt * 32;
    const size_t krow = ((size_t)(b * 1024 + j0 + l31)) * 2048 + hofs + q2 * 8;
    f32x16 S = z16;
#pragma unroll
    for (int c = 0; c < 8; ++c) {
      bf16x8 k8h = *(const bf16x8*)(Kh + krow + c * 16);
      bf16x8 k8l = *(const bf16x8*)(Kl + krow + c * 16);
      __builtin_amdgcn_s_setprio(1);
      S = __builtin_amdgcn_mfma_f32_32x32x16_bf16(qh[c], k8h, S, 0, 0, 0);
      S = __builtin_amdgcn_mfma_f32_32x32x16_bf16(qh[c], k8l, S, 0, 0, 0);
      S = __builtin_amdgcn_mfma_f32_32x32x16_bf16(ql[c], k8h, S, 0, 0, 0);
      __builtin_amdgcn_s_setprio(0);
    }
    if (kt == qt) {
#pragma unroll
      for (int r = 0; r < 16; ++r)
        if (l31 > rowq[r]) S[r] = -3e38f;
    }
#pragma unroll
    for (int r = 0; r < 16; ++r) {
      const float p = EXP2F(S[r] * SC2);
      lr[r] += p;
      const u16 ph = bf16_rne(p);
      const u16 pl = bf16_rne(p - __uint_as_float((uint32_t)ph << 16));
      Pw[rowq[r] * PLD + l31] = (uint32_t)ph | ((uint32_t)pl << 16);
    }
#pragma unroll
    for (int s = 0; s < 2; ++s) {
      const uint32_t* rp = Pw + l31 * PLD + s * 16 + q2 * 8;
      uint2 a0 = *(const uint2*)(rp + 0);
      uint2 a1 = *(const uint2*)(rp + 2);
      uint2 a2 = *(const uint2*)(rp + 4);
      uint2 a3 = *(const uint2*)(rp + 6);
      u16x8 uh, ul;
      uh[0] = (u16)a0.x; ul[0] = (u16)(a0.x >> 16);
      uh[1] = (u16)a0.y; ul[1] = (u16)(a0.y >> 16);
      uh[2] = (u16)a1.x; ul[2] = (u16)(a1.x >> 16);
      uh[3] = (u16)a1.y; ul[3] = (u16)(a1.y >> 16);
      uh[4] = (u16)a2.x; ul[4] = (u16)(a2.x >> 16);
      uh[5] = (u16)a2.y; ul[5] = (u16)(a2.y >> 16);
      uh[6] = (u16)a3.x; ul[6] = (u16)(a3.x >> 16);
      uh[7] = (u16)a3.y; ul[7] = (u16)(a3.y >> 16);
      bf16x8 p8h = __builtin_bit_cast(bf16x8, uh);
      bf16x8 p8l = __builtin_bit_cast(bf16x8, ul);
      const size_t vrow = ((size_t)(bh * 128 + l31)) * 1024 + j0 + s * 16 + q2 * 8;
#pragma unroll
      for (int dt = 0; dt < 4; ++dt) {
        bf16x8 v8h = *(const bf16x8*)(Vth + vrow + (size_t)dt * 32768);
        bf16x8 v8l = *(const bf16x8*)(Vtl + vrow + (size_t)dt * 32768);
        __builtin_amdgcn_s_setprio(1);
        Oacc[dt] = __builtin_amdgcn_mfma_f32_32x32x16_bf16(p8h, v8h, Oacc[dt], 0, 0, 0);
        Oacc[dt] = __builtin_amdgcn_mfma_f32_32x32x16_bf16(p8h, v8l, Oacc[dt], 0, 0, 0);
        Oacc[dt] = __builtin_amdgcn_mfma_f32_32x32x16_bf16(p8l, v8h, Oacc[dt], 0, 0, 0);
        __builtin_amdgcn_s_setprio(0);
      }
    }
  }

#pragma unroll
  for (int r = 0; r < 16; ++r) {
    float t = lr[r];
    t += __shfl_xor(t, 1);
    t += __shfl_xor(t, 2);
    t += __shfl_xor(t, 4);
    t += __shfl_xor(t, 8);
    t += __shfl_xor(t, 16);
    lr[r] = t;
  }
  if (l31 == 0) {
#pragma unroll
    for (int r = 0; r < 16; ++r) lsh[w][rowq[r]] = lr[r];
  }
  if (w == 0) {
#pragma unroll
    for (int dt = 0; dt < 4; ++dt)
#pragma unroll
      for (int r = 0; r < 16; ++r) Osum[rowq[r] * 128 + dt * 32 + l31] = Oacc[dt][r];
  }
  __syncthreads();
  if (w == 1) {
#pragma unroll
    for (int dt = 0; dt < 4; ++dt)
#pragma unroll
      for (int r = 0; r < 16; ++r) Osum[rowq[r] * 128 + dt * 32 + l31] += Oacc[dt][r];
  }
  __syncthreads();
  if (w == 2) {
#pragma unroll
    for (int dt = 0; dt < 4; ++dt)
#pragma unroll
      for (int r = 0; r < 16; ++r) Osum[rowq[r] * 128 + dt * 32 + l31] += Oacc[dt][r];
  }
  __syncthreads();
  if (w == 3) {
#pragma unroll
    for (int dt = 0; dt < 4; ++dt)
#pragma unroll
      for (int r = 0; r < 16; ++r) Osum[rowq[r] * 128 + dt * 32 + l31] += Oacc[dt][r];
  }
  __syncthreads();
  // ---- fused qdq epilogue (e5m2): one quant block per row ----
  const int row = w * 8 + (lane >> 3);
  const int c0 = (lane & 7) * 16;
  const float inv = 1.0f / (lsh[0][row] + lsh[1][row] + lsh[2][row] + lsh[3][row]);
  float vq[16];
  float am = 0.f;
#pragma unroll
  for (int i2 = 0; i2 < 4; ++i2) {
    float4 v = *(const float4*)(Osum + row * 128 + c0 + i2 * 4);
    vq[i2 * 4 + 0] = v.x * inv;
    vq[i2 * 4 + 1] = v.y * inv;
    vq[i2 * 4 + 2] = v.z * inv;
    vq[i2 * 4 + 3] = v.w * inv;
  }
#pragma unroll
  for (int t = 0; t < 16; ++t) am = fmaxf(am, fabsf(vq[t]));
  am = fmaxf(am, __shfl_xor(am, 1));
  am = fmaxf(am, __shfl_xor(am, 2));
  am = fmaxf(am, __shfl_xor(am, 4));
  const float sc = fmaxf(am / 57344.f, 1e-12f);
  uint8_t qb8[16];
#pragma unroll
  for (int t = 0; t < 16; ++t) qb8[t] = q_e5(vq[t], sc);
  const int token = b * 1024 + i0 + row;
  *(uint4*)(Aqo + (size_t)token * 2048 + hofs + c0) = *(const uint4*)qb8;
  if ((lane & 7) == 0) sTo[(size_t)(bh & 15) * 2048 + token] = sc;
}

// ---------------------------------------------------------------------------
// MX-fp8 GEMM (r0-proven simple structure): 128x128 tile, BK=128, single
// 32KB-buffer stage->sync->compute loop; 4 blocks/CU TLP hides staging
// latency (m114). QOUT=1 (fc1): instead of f32 out, apply bias+gelu then
// quantize per (row, n-tile) quant block (tile = exactly one 128-wide block)
// and write fp8 bytes + transposed scales — skips the 64MB hb buffer and the
// qdq(hb) dispatch. Exact max + identical encode -> bit-identical.
// FMT: 0 = e4m3fn, 1 = e5m2.
// ---------------------------------------------------------------------------
template <int FMT, int QOUT>
__global__ __launch_bounds__(256, 2) void gemm_simple(
    const uint8_t* __restrict__ A, const float* __restrict__ sxT,
    const uint8_t* __restrict__ W, const float* __restrict__ wsc,
    const float* __restrict__ bias, float* __restrict__ out,
    uint8_t* __restrict__ outq, float* __restrict__ sTq,
    int M, int N, int K, int gelu, int seg_shift, int Nw) {
  __shared__ uint8_t As[128 * 128];
  __shared__ uint8_t Ws[128 * 128];
  __shared__ float rowred[2][128];
  const int tid = threadIdx.x;
  const int lane = tid & 63;
  const int wave = tid >> 6;
  const int wm = (wave >> 1) * 64;
  const int wn = (wave & 1) * 64;
  const int l31 = lane & 31;
  const int q2 = lane >> 5;
  const int bm = blockIdx.y * 128;
  const int bn = blockIdx.x * 128;

  // staging: instr s covers rows [s*32 + wave*8, +8); LDS dest = uniform +
  // lane*16 (required); global chunk XOR-swizzled so LDS chunk = orig^(row&7).
  const int srow = wave * 8 + (lane >> 3);
  const int gchunk = (lane & 7) ^ (lane >> 3);
  const uint8_t* ga = A + (size_t)(bm + srow) * K + gchunk * 16;
  const uint8_t* gw = W + (size_t)(bn + srow) * K + gchunk * 16;
  uint8_t* la = As + srow * 128 + (lane & 7) * 16;
  uint8_t* lw = Ws + srow * 128 + (lane & 7) * 16;

  const f32x16 z16 = {0.f};
  f32x16 acc[2][2] = {{z16, z16}, {z16, z16}};

  const int nk = K >> 7;
  for (int kt = 0; kt < nk; ++kt) {
    __syncthreads();
#pragma unroll
    for (int s = 0; s < 4; ++s) {
      gl_lds16(ga + (size_t)s * 32 * K, la + s * 4096);
      gl_lds16(gw + (size_t)s * 32 * K, lw + s * 4096);
    }
    ga += 128;
    gw += 128;
    __syncthreads();
    f32x16 chk[2][2] = {{z16, z16}, {z16, z16}};
#pragma unroll
    for (int mf = 0; mf < 2; ++mf) {  // two K=64 halves of the 128-K tile
      i32x8 af[2], bf2[2];
      const int c = mf * 4 + q2 * 2;  // lane's first 16B chunk (k = c*16)
#pragma unroll
      for (int i = 0; i < 2; ++i) {
        const int r = wm + i * 32 + l31;
        const uint8_t* Ar = As + r * 128;
        const int s7 = r & 7;
        af[i] = pack8(*(const uint4*)(Ar + ((c ^ s7) * 16)),
                      *(const uint4*)(Ar + (((c + 1) ^ s7) * 16)));
      }
#pragma unroll
      for (int j = 0; j < 2; ++j) {
        const int r = wn + j * 32 + l31;
        const uint8_t* Wr = Ws + r * 128;
        const int s7 = r & 7;
        bf2[j] = pack8(*(const uint4*)(Wr + ((c ^ s7) * 16)),
                       *(const uint4*)(Wr + (((c + 1) ^ s7) * 16)));
      }
#pragma unroll
      for (int i = 0; i < 2; ++i)
#pragma unroll
        for (int j = 0; j < 2; ++j)
          chk[i][j] = __builtin_amdgcn_mfma_scale_f32_32x32x64_f8f6f4(
              af[i], bf2[j], chk[i][j], FMT, FMT, 0, 0x7F7F7F7F, 0, 0x7F7F7F7F);
    }
    // fold the per-128-K activation scale (exact)
#pragma unroll
    for (int i = 0; i < 2; ++i) {
#pragma unroll
      for (int rg = 0; rg < 4; ++rg) {
        const f32x4 sv = *(const f32x4*)(sxT + (size_t)kt * M + bm + wm + i * 32 + rg * 8 + q2 * 4);
#pragma unroll
        for (int j = 0; j < 2; ++j)
#pragma unroll
          for (int rr = 0; rr < 4; ++rr)
            acc[i][j][rg * 4 + rr] += sv[rr] * chk[i][j][rg * 4 + rr];
      }
    }
  }

  if (QOUT) {
    // ---- fused bias+gelu+qdq epilogue (e4m3; fc1) ----
    // materialize post-gelu values in place
#pragma unroll
    for (int i = 0; i < 2; ++i) {
#pragma unroll
      for (int j = 0; j < 2; ++j) {
        const int n = bn + wn + j * 32 + l31;
        const float wsn = wsc[n >> 7];
        const float bv = bias[n];
#pragma unroll
        for (int reg = 0; reg < 16; ++reg) {
          float v = acc[i][j][reg] * wsn + bv;
          acc[i][j][reg] = 0.5f * v * (1.f + erff(v * 0.70710678118654752440f));
        }
      }
    }
    // per-row absmax over the 128-wide tile (= one quant block):
    // wave-pair {wn=0, wn=64} each reduce their 64 cols, combine via LDS.
#pragma unroll
    for (int i = 0; i < 2; ++i) {
      float am2[16];
#pragma unroll
      for (int reg = 0; reg < 16; ++reg)
        am2[reg] = fmaxf(fabsf(acc[i][0][reg]), fabsf(acc[i][1][reg]));
#pragma unroll
      for (int reg = 0; reg < 16; ++reg) {
        am2[reg] = fmaxf(am2[reg], __shfl_xor(am2[reg], 1));
        am2[reg] = fmaxf(am2[reg], __shfl_xor(am2[reg], 2));
        am2[reg] = fmaxf(am2[reg], __shfl_xor(am2[reg], 4));
        am2[reg] = fmaxf(am2[reg], __shfl_xor(am2[reg], 8));
        am2[reg] = fmaxf(am2[reg], __shfl_xor(am2[reg], 16));
      }
      if (l31 == 0) {
#pragma unroll
        for (int reg = 0; reg < 16; ++reg)
          rowred[wave & 1][wm + i * 32 + (reg & 3) + 8 * (reg >> 2) + 4 * q2] = am2[reg];
      }
    }
    __syncthreads();
#pragma unroll
    for (int i = 0; i < 2; ++i) {
#pragma unroll
      for (int reg = 0; reg < 16; ++reg) {
        const int rloc = wm + i * 32 + (reg & 3) + 8 * (reg >> 2) + 4 * q2;
        const float sc = fmaxf(fmaxf(rowred[0][rloc], rowred[1][rloc]) / 448.f, 1e-12f);
        const int m = bm + rloc;
#pragma unroll
        for (int j = 0; j < 2; ++j)
          outq[(size_t)m * N + bn + wn + j * 32 + l31] = q_e4(acc[i][j][reg], sc);
        if ((wave & 1) == 0 && l31 == 0) sTq[(size_t)(bn >> 7) * M + m] = sc;
      }
    }
    return;
  }

#pragma unroll
  for (int i = 0; i < 2; ++i) {
#pragma unroll
    for (int j = 0; j < 2; ++j) {
      const int n = bn + wn + j * 32 + l31;
      const float wsn = wsc[n >> 7];
      const float bv = bias ? bias[n] : 0.f;
      const int seg = n >> seg_shift;
      const int col = n & ((1 << seg_shift) - 1);
      float* op = out + (size_t)seg * M * Nw + col;
#pragma unroll
      for (int reg = 0; reg < 16; ++reg) {
        const int m = bm + wm + i * 32 + (reg & 3) + 8 * (reg >> 2) + 4 * q2;
        float v = acc[i][j][reg] * wsn + bv;
        if (gelu) v = 0.5f * v * (1.f + erff(v * 0.70710678118654752440f));
        op[(size_t)m * Nw] = v;
      }
    }
  }
}

// out = LN(a + b) * (g*gs_rep) + (bb*bs_rep), eps=1e-5, C=2048, one block/row.
// QOUT=1 additionally quantizes the output (e4m3, 16 blocks/row) and writes
// fp8 bytes + transposed scales — removes the standalone qdq(ln1o) pass.
template <int QOUT>
__global__ __launch_bounds__(256) void ln_kernel(
    const float* __restrict__ a, const float* __restrict__ b2,
    const float* __restrict__ g, const float* __restrict__ gs,
    const float* __restrict__ bb, const float* __restrict__ bs,
    float* __restrict__ out, uint8_t* __restrict__ outq, float* __restrict__ sT,
    int C) {
  __shared__ float red[4];
  __shared__ float wred[8][4];
  const int tid = threadIdx.x;
  const int row = blockIdx.x;
  const float* pa = a + (size_t)row * C;
  const float* pb = b2 + (size_t)row * C;
  float v[8];
  float sum = 0.f;
#pragma unroll
  for (int k = 0; k < 8; ++k) {
    const int c = tid + (k << 8);
    v[k] = pa[c] + pb[c];
    sum += v[k];
  }
#pragma unroll
  for (int m = 32; m >= 1; m >>= 1) sum += __shfl_xor(sum, m);
  if ((tid & 63) == 0) red[tid >> 6] = sum;
  __syncthreads();
  const float mean = (red[0] + red[1] + red[2] + red[3]) * (1.f / 2048.f);
  __syncthreads();
  float sq = 0.f;
#pragma unroll
  for (int k = 0; k < 8; ++k) {
    const float d = v[k] - mean;
    sq += d * d;
  }
#pragma unroll
  for (int m = 32; m >= 1; m >>= 1) sq += __shfl_xor(sq, m);
  if ((tid & 63) == 0) red[tid >> 6] = sq;
  __syncthreads();
  const float var = (red[0] + red[1] + red[2] + red[3]) * (1.f / 2048.f);
  const float inv = 1.0f / sqrtf(var + 1e-5f);
  float* po = out + (size_t)row * C;
  float o[8];
#pragma unroll
  for (int k = 0; k < 8; ++k) {
    const int c = tid + (k << 8);
    o[k] = (v[k] - mean) * inv * (g[c] * gs[c >> 7]) + bb[c] * bs[c >> 7];
    po[c] = o[k];
  }
  if (QOUT) {
    const int w = tid >> 6;
#pragma unroll
    for (int k = 0; k < 8; ++k) {
      float am = fabsf(o[k]);
      am = fmaxf(am, __shfl_xor(am, 1));
      am = fmaxf(am, __shfl_xor(am, 2));
      am = fmaxf(am, __shfl_xor(am, 4));
      am = fmaxf(am, __shfl_xor(am, 8));
      am = fmaxf(am, __shfl_xor(am, 16));
      am = fmaxf(am, __shfl_xor(am, 32));
      if ((tid & 63) == 0) wred[k][w] = am;
    }
    __syncthreads();
    const int hsel = (tid >> 7) * 2;
#pragma unroll
    for (int k = 0; k < 8; ++k) {
      const float bm = fmaxf(wred[k][hsel], wred[k][hsel + 1]);
      const float sc = fmaxf(bm / 448.f, 1e-12f);
      const int c = tid + (k << 8);
      outq[(size_t)row * C + c] = q_e4(o[k], sc);
      if ((tid & 127) == 0) sT[(size_t)((k << 1) | (tid >> 7)) * 2048 + row] = sc;
    }
  }
}

extern "C" void kernel_launch(void* const* d_in, const int* in_sizes, int n_in,
                              void* d_out, int out_size, void* d_ws, size_t ws_size,
                              hipStream_t stream) {
  const int C = 2048, MLP = 8192;
  const int M = 2048;  // B*T tokens

  const float* x = (const float*)d_in[0];
  const float* wq = (const float*)d_in[2];
  const float* qs = (const float*)d_in[3];
  const float* wk = (const float*)d_in[4];
  const float* ks = (const float*)d_in[5];
  const float* wv = (const float*)d_in[6];
  const float* vs = (const float*)d_in[7];
  const float* wo = (const float*)d_in[8];
  const float* os_ = (const float*)d_in[9];
  const float* fc1_w = (const float*)d_in[10];
  const float* fc1_s = (const float*)d_in[11];
  const float* fc1_b = (const float*)d_in[12];
  const float* fc2_w = (const float*)d_in[13];
  const float* fc2_s = (const float*)d_in[14];
  const float* fc2_b = (const float*)d_in[15];
  const float* ln1_g = (const float*)d_in[16];
  const float* ln1_gs = (const float*)d_in[17];
  const float* ln1_b = (const float*)d_in[18];
  const float* ln1_bs = (const float*)d_in[19];
  const float* ln2_g = (const float*)d_in[20];
  const float* ln2_gs = (const float*)d_in[21];
  const float* ln2_b = (const float*)d_in[22];
  const float* ln2_bs = (const float*)d_in[23];

  char* ws = (char*)d_ws;
  const size_t o_Aq = 0;           // 32 MB; aliased by Kh/Kl/Vth/Vtl during attention
  const size_t o_Wb = 33554432;    // 32 MB fp8 weights
  const size_t o_sx = 67108864;    // 512 KB activation scales (transposed)
  const size_t o_ln1 = 67633152;   // 16 MB
  const size_t o_q = 84410368;     // 16 MB
  const size_t o_k = 101187584;    // 16 MB (contiguous after o_q)
  const size_t o_v = 117964800;    // 16 MB (contiguous after o_k)
  const size_t o_ctx = 134742016;  // 16 MB (attn fused fp8 out: 4 MB used)
  const size_t o_attn = 151519232; // 16 MB -> end 168296448
  const size_t o_ffn = o_attn;     // ffn reuses attn_out (dead by fc2)
  if (ws_size < 168296448ull) return;

  uint8_t* Aq = (uint8_t*)(ws + o_Aq);        // qdq(x) out; later ln1-fused out
  uint8_t* Wb = (uint8_t*)(ws + o_Wb);
  float* sx = (float*)(ws + o_sx);
  float* wsc3 = (float*)(ws + o_sx + 262144); // dead part of sx region during qkv
  float* ln1o = (float*)(ws + o_ln1);
  float* qb = (float*)(ws + o_q);
  float* kb = (float*)(ws + o_k);
  float* vb = (float*)(ws + o_v);
  uint8_t* Aq2 = (uint8_t*)(ws + o_ctx);      // attn fused fp8 out (4 MB)
  float* attn_out = (float*)(ws + o_attn);
  uint8_t* Aq3 = (uint8_t*)(ws + o_q);        // fc1 fused fp8 out (16 MB; qb dead)
  float* sxk = (float*)(ws + o_k);            // fc2 A-scales (512 KB; kb dead)
  float* ffn = (float*)(ws + o_ffn);
  float* outp = (float*)d_out;
  // attention splits alias the (dead after qkv GEMM) Aq region
  u16* Kh = (u16*)(ws + o_Aq);
  u16* Kl = (u16*)(ws + o_Aq + 8388608);
  u16* Vth = (u16*)(ws + o_Aq + 16777216);
  u16* Vtl = (u16*)(ws + o_Aq + 25165824);

  const float E5_MAX = 57344.f, E5_MINN = 6.103515625e-05f, E5_SUBQ = 1.52587890625e-05f;
  const float E4_MAX = 448.f, E4_MINN = 0.015625f, E4_SUBQ = 0.001953125f;

  const dim3 blk(256);
  const int wc_qkv = (C * C / 4 + 255) / 256;
  const int wc_fc = (C * MLP / 4 + 255) / 256;

  // ---- fused qkv projection (e5m2 = fmt 1): one GEMM (N=6144) ----
  qdq_kernel<<<M * (C / 128) / 4, blk, 0, stream>>>(x, Aq, sx, M * (C / 128), 4, E5_MAX, E5_MINN, E5_SUBQ, 2, 15);
  w3_to_fp8_kernel<<<dim3(wc_qkv, 3), blk, 0, stream>>>(wq, wk, wv, Wb, C * C / 4);
  concat3_kernel<<<1, 64, 0, stream>>>(qs, ks, vs, wsc3, C / 128);
  gemm_simple<1, 0><<<dim3(3 * C / 128, M / 128), blk, 0, stream>>>(
      Aq, sx, Wb, wsc3, nullptr, qb, nullptr, nullptr, M, 3 * C, C, 0, 11, C);

  // ---- attention (bf16x3 MFMA flash; fused e5m2 qdq epilogue) ----
  split_bf16_kernel<<<(M * C / 4 + 255) / 256, blk, 0, stream>>>(kb, Kh, Kl, M * C / 4);
  vtrans_kernel<<<dim3(16, 2, 32), blk, 0, stream>>>(vb, Vth, Vtl);
  attn_wave_kernel<<<dim3(32, 32), blk, 0, stream>>>(qb, Kh, Kl, Vth, Vtl, Aq2, sx);

  // ---- attn-out projection (reads fused fp8 ctx directly) ----
  w_to_fp8_kernel<<<wc_qkv, blk, 0, stream>>>(wo, Wb, C * C / 4, 2, 15);
  gemm_simple<1, 0><<<dim3(C / 128, M / 128), blk, 0, stream>>>(
      Aq2, sx, Wb, os_, nullptr, attn_out, nullptr, nullptr, M, C, C, 0, 30, C);

  // ---- ln1 (fused e4m3 qdq: emits fc1's A + scales directly) ----
  ln_kernel<1><<<M, blk, 0, stream>>>(x, attn_out, ln1_g, ln1_gs, ln1_b, ln1_bs,
                                      ln1o, Aq, sx, C);

  // ---- MLP (e4m3fn = fmt 0) ----
  w_to_fp8_kernel<<<wc_fc, blk, 0, stream>>>(fc1_w, Wb, C * MLP / 4, 3, 7);
  // fc1 with fused bias+gelu+qdq epilogue: writes fp8 Aq3 + sxk, no f32 hb
  gemm_simple<0, 1><<<dim3(MLP / 128, M / 128), blk, 0, stream>>>(
      Aq, sx, Wb, fc1_s, fc1_b, nullptr, Aq3, sxk, M, MLP, C, 1, 30, MLP);

  w_to_fp8_kernel<<<wc_fc, blk, 0, stream>>>(fc2_w, Wb, C * MLP / 4, 3, 7);
  gemm_simple<0, 0><<<dim3(C / 128, M / 128), blk, 0, stream>>>(
      Aq3, sxk, Wb, fc2_s, fc2_b, ffn, nullptr, nullptr, M, C, MLP, 0, 30, C);

  ln_kernel<0><<<M, blk, 0, stream>>>(ln1o, ffn, ln2_g, ln2_gs, ln2_b, ln2_bs,
                                      outp, nullptr, nullptr, C);
}

// Round 9
// 655.074 us; speedup vs baseline: 1.0612x; 1.0032x over previous
//
#include <hip/hip_runtime.h>
#include <cstdint>

// ---------------------------------------------------------------------------
// FP8TransformerLayer on MI355X (gfx950) — round 13: qkv-epilogue fusion of
// the attention preprocessing. r8 fused all qdq passes (bit-identical,
// absmax 0.0527); the remaining glue was qkv's 50MB f32 out + split_bf16(K)
// + vtrans(V) + per-block Q-split in attn. Each qkv block's 128x128 tile is
// exactly one head x 128 tokens, so the epilogue now emits Qh/Ql, Kh/Kl
// elementwise and Vth/Vtl transposed via the (dead after the main loop)
// 33KB LDS as packed (hi|lo<<16) u32, written coalesced. Identical
// bf16_rne math on identical f32 values -> bit-identical attention inputs.
// split_bf16 + vtrans dispatches removed; 32MB re-reads removed.
// GEMM structure r0-proven simple 128^2 (at its shape ceiling, r7 analysis);
// fc1/ln1/attn epilogue fusions from r8; attention (256,2)+setprio.
// B=2 T=1024 C=2048 H=16 HD=128 MLP=8192, BS=128 quant blocks.
// ---------------------------------------------------------------------------

typedef __bf16 bf16x8 __attribute__((ext_vector_type(8)));
typedef unsigned short u16x8 __attribute__((ext_vector_type(8)));
typedef float f32x4 __attribute__((ext_vector_type(4)));
typedef float f32x16 __attribute__((ext_vector_type(16)));
typedef int i32x8 __attribute__((ext_vector_type(8)));
typedef unsigned short u16;

#if __has_builtin(__builtin_amdgcn_exp2f)
#define EXP2F(x) __builtin_amdgcn_exp2f(x)
#else
#define EXP2F(x) exp2f(x)
#endif

__device__ __forceinline__ void gl_lds16(const void* g, void* l) {
  __builtin_amdgcn_global_load_lds(
      (const __attribute__((address_space(1))) void*)g,
      (__attribute__((address_space(3))) void*)l, 16, 0, 0);
}

struct u4x2 { uint4 a, b; };
__device__ __forceinline__ i32x8 pack8(uint4 lo, uint4 hi) {
  u4x2 t{lo, hi};
  return __builtin_bit_cast(i32x8, t);
}

__device__ __forceinline__ u16 bf16_rne(float v) {
  uint32_t u = __float_as_uint(v);
  u += 0x7FFFu + ((u >> 16) & 1u);
  return (u16)(u >> 16);
}

__device__ __forceinline__ float fp8_round(float v, int mbits, float minnorm, float subq) {
  float av = fabsf(v);
  if (av < minnorm) {
    return rintf(v / subq) * subq;  // subnormal grid, RNE
  }
  uint32_t u = __float_as_uint(v);
  const int shift = 23 - mbits;
  const uint32_t mask = (1u << shift) - 1u;
  const uint32_t rem = u & mask;
  uint32_t base = u & ~mask;
  const uint32_t half = 1u << (shift - 1);
  if (rem > half || (rem == half && ((base >> shift) & 1u))) base += (1u << shift);
  return __uint_as_float(base);
}

// exact byte encode of an fp8-representable f32 (e4m3fn: mbits=3,bias=7;
// e5m2: mbits=2,bias=15)
__device__ __forceinline__ uint8_t fp8_encode(float v, int mbits, int bias) {
  uint32_t u = __float_as_uint(v);
  uint32_t sign = (u >> 31) << 7;
  if ((u & 0x7FFFFFFFu) == 0) return (uint8_t)sign;
  int e = (int)((u >> 23) & 255u) - 127;
  if (e >= 1 - bias) {
    uint32_t mant = (u >> (23 - mbits)) & ((1u << mbits) - 1u);
    return (uint8_t)(sign | ((uint32_t)(e + bias) << mbits) | mant);
  }
  // subnormal: |v| * 2^(bias-1+mbits) is an exact small integer
  float q = fabsf(v) * __uint_as_float((uint32_t)(127 + bias - 1 + mbits) << 23);
  return (uint8_t)(sign | (uint32_t)q);
}

// quantize one value with E5M2 / E4M3 constants
__device__ __forceinline__ uint8_t q_e5(float v, float sc) {
  return fp8_encode(fp8_round(v / sc, 2, 6.103515625e-05f, 1.52587890625e-05f), 2, 15);
}
__device__ __forceinline__ uint8_t q_e4(float v, float sc) {
  return fp8_encode(fp8_round(v / sc, 3, 0.015625f, 0.001953125f), 3, 7);
}

// one 64-lane wave per 128-element quant block; fp8 BYTES out; scale written
// TRANSPOSED: sT[kb * Mtot + m], kb = wid & (kbs-1), m = wid >> kbshift.
__global__ __launch_bounds__(256) void qdq_kernel(
    const float* __restrict__ x, uint8_t* __restrict__ q, float* __restrict__ sT,
    int nblk, int kbshift, float fmax, float minnorm, float subq, int mbits, int bias) {
  const int wid = blockIdx.x * 4 + (threadIdx.x >> 6);
  if (wid >= nblk) return;
  const int lane = threadIdx.x & 63;
  const size_t base = (size_t)wid * 128 + (size_t)lane * 2;
  float2 v = *(const float2*)(x + base);
  float am = fmaxf(fabsf(v.x), fabsf(v.y));
#pragma unroll
  for (int m = 32; m >= 1; m >>= 1) am = fmaxf(am, __shfl_xor(am, m));
  const float sc = fmaxf(am / fmax, 1e-12f);
  const float q0 = fp8_round(v.x / sc, mbits, minnorm, subq);
  const float q1 = fp8_round(v.y / sc, mbits, minnorm, subq);
  uchar2 o;
  o.x = fp8_encode(q0, mbits, bias);
  o.y = fp8_encode(q1, mbits, bias);
  *(uchar2*)(q + base) = o;
  if (lane == 0) {
    const int kbs = 1 << kbshift;
    const int m = wid >> kbshift;
    const int kb = wid & (kbs - 1);
    sT[(size_t)kb * (nblk >> kbshift) + m] = sc;
  }
}

// weights are fp8-valued f32 -> exact byte encode
__global__ __launch_bounds__(256) void w_to_fp8_kernel(
    const float* __restrict__ in, uint8_t* __restrict__ out, int n4, int mbits, int bias) {
  const int i = blockIdx.x * 256 + threadIdx.x;
  if (i >= n4) return;
  float4 v = ((const float4*)in)[i];
  uchar4 o;
  o.x = fp8_encode(v.x, mbits, bias);
  o.y = fp8_encode(v.y, mbits, bias);
  o.z = fp8_encode(v.z, mbits, bias);
  o.w = fp8_encode(v.w, mbits, bias);
  *(uchar4*)(out + (size_t)i * 4) = o;
}

// 3 same-size weights -> fp8 bytes in one dispatch (e5m2)
__global__ __launch_bounds__(256) void w3_to_fp8_kernel(
    const float* __restrict__ a, const float* __restrict__ b,
    const float* __restrict__ c, uint8_t* __restrict__ out, int n4) {
  const int i = blockIdx.x * 256 + threadIdx.x;
  if (i >= n4) return;
  const float* in = blockIdx.y == 0 ? a : (blockIdx.y == 1 ? b : c);
  float4 v = ((const float4*)in)[i];
  uchar4 o;
  o.x = fp8_encode(v.x, 2, 15);
  o.y = fp8_encode(v.y, 2, 15);
  o.z = fp8_encode(v.z, 2, 15);
  o.w = fp8_encode(v.w, 2, 15);
  *(uchar4*)(out + (size_t)blockIdx.y * n4 * 4 + (size_t)i * 4) = o;
}

// concat 3 small scale vectors (n each) into o[0..3n)
__global__ void concat3_kernel(const float* __restrict__ a, const float* __restrict__ b,
                               const float* __restrict__ c, float* __restrict__ o, int n) {
  const int i = threadIdx.x;
  if (i < n) { o[i] = a[i]; o[n + i] = b[i]; o[2 * n + i] = c[i]; }
}

// ---------------------------------------------------------------------------
// Wave-independent flash attention, fused qdq epilogue (r8). Q now arrives
// PRE-SPLIT (Qh/Ql u16 from the qkv epilogue) — same values, same layout.
// (256,2): ~184 unified VGPR+AGPR demand; tighter caps spill (r9 lesson).
// ---------------------------------------------------------------------------
__global__ __launch_bounds__(256, 2) void attn_wave_kernel(
    const u16* __restrict__ Qh, const u16* __restrict__ Ql,
    const u16* __restrict__ Kh, const u16* __restrict__ Kl,
    const u16* __restrict__ Vth, const u16* __restrict__ Vtl,
    uint8_t* __restrict__ Aqo, float* __restrict__ sTo) {
  constexpr int PLD = 34;
  __shared__ uint32_t Psm[4][32 * PLD];
  __shared__ float Osum[32 * 128];
  __shared__ float lsh[4][32];

  const int tid = threadIdx.x;
  const int w = tid >> 6;
  const int lane = tid & 63;
  const int l31 = lane & 31;
  const int q2 = lane >> 5;
  const int bh = blockIdx.x;
  const int b = bh >> 4;
  const int hofs = (bh & 15) * 128;
  const int qt = 31 - (int)blockIdx.y;
  const int i0 = qt * 32;
  const float SC2 = 0.12752698f;  // log2(e)/sqrt(128)

  bf16x8 qh[8], ql[8];
  {
    const size_t qrow = ((size_t)(b * 1024 + i0 + l31)) * 2048 + hofs + q2 * 8;
#pragma unroll
    for (int c = 0; c < 8; ++c) {
      qh[c] = *(const bf16x8*)(Qh + qrow + c * 16);
      ql[c] = *(const bf16x8*)(Ql + qrow + c * 16);
    }
  }

  const f32x16 z16 = {0.f};
  f32x16 Oacc[4] = {z16, z16, z16, z16};
  float lr[16];
#pragma unroll
  for (int r = 0; r < 16; ++r) lr[r] = 0.f;
  int rowq[16];
#pragma unroll
  for (int r = 0; r < 16; ++r) rowq[r] = (r & 3) + 8 * (r >> 2) + 4 * q2;

  uint32_t* Pw = Psm[w];
  for (int kt = w; kt <= qt; kt += 4) {
    const int j0 = kt * 32;
    const size_t krow = ((size_t)(b * 1024 + j0 + l31)) * 2048 + hofs + q2 * 8;
    f32x16 S = z16;
#pragma unroll
    for (int c = 0; c < 8; ++c) {
      bf16x8 k8h = *(const bf16x8*)(Kh + krow + c * 16);
      bf16x8 k8l = *(const bf16x8*)(Kl + krow + c * 16);
      __builtin_amdgcn_s_setprio(1);
      S = __builtin_amdgcn_mfma_f32_32x32x16_bf16(qh[c], k8h, S, 0, 0, 0);
      S = __builtin_amdgcn_mfma_f32_32x32x16_bf16(qh[c], k8l, S, 0, 0, 0);
      S = __builtin_amdgcn_mfma_f32_32x32x16_bf16(ql[c], k8h, S, 0, 0, 0);
      __builtin_amdgcn_s_setprio(0);
    }
    if (kt == qt) {
#pragma unroll
      for (int r = 0; r < 16; ++r)
        if (l31 > rowq[r]) S[r] = -3e38f;
    }
#pragma unroll
    for (int r = 0; r < 16; ++r) {
      const float p = EXP2F(S[r] * SC2);
      lr[r] += p;
      const u16 ph = bf16_rne(p);
      const u16 pl = bf16_rne(p - __uint_as_float((uint32_t)ph << 16));
      Pw[rowq[r] * PLD + l31] = (uint32_t)ph | ((uint32_t)pl << 16);
    }
#pragma unroll
    for (int s = 0; s < 2; ++s) {
      const uint32_t* rp = Pw + l31 * PLD + s * 16 + q2 * 8;
      uint2 a0 = *(const uint2*)(rp + 0);
      uint2 a1 = *(const uint2*)(rp + 2);
      uint2 a2 = *(const uint2*)(rp + 4);
      uint2 a3 = *(const uint2*)(rp + 6);
      u16x8 uh, ul;
      uh[0] = (u16)a0.x; ul[0] = (u16)(a0.x >> 16);
      uh[1] = (u16)a0.y; ul[1] = (u16)(a0.y >> 16);
      uh[2] = (u16)a1.x; ul[2] = (u16)(a1.x >> 16);
      uh[3] = (u16)a1.y; ul[3] = (u16)(a1.y >> 16);
      uh[4] = (u16)a2.x; ul[4] = (u16)(a2.x >> 16);
      uh[5] = (u16)a2.y; ul[5] = (u16)(a2.y >> 16);
      uh[6] = (u16)a3.x; ul[6] = (u16)(a3.x >> 16);
      uh[7] = (u16)a3.y; ul[7] = (u16)(a3.y >> 16);
      bf16x8 p8h = __builtin_bit_cast(bf16x8, uh);
      bf16x8 p8l = __builtin_bit_cast(bf16x8, ul);
      const size_t vrow = ((size_t)(bh * 128 + l31)) * 1024 + j0 + s * 16 + q2 * 8;
#pragma unroll
      for (int dt = 0; dt < 4; ++dt) {
        bf16x8 v8h = *(const bf16x8*)(Vth + vrow + (size_t)dt * 32768);
        bf16x8 v8l = *(const bf16x8*)(Vtl + vrow + (size_t)dt * 32768);
        __builtin_amdgcn_s_setprio(1);
        Oacc[dt] = __builtin_amdgcn_mfma_f32_32x32x16_bf16(p8h, v8h, Oacc[dt], 0, 0, 0);
        Oacc[dt] = __builtin_amdgcn_mfma_f32_32x32x16_bf16(p8h, v8l, Oacc[dt], 0, 0, 0);
        Oacc[dt] = __builtin_amdgcn_mfma_f32_32x32x16_bf16(p8l, v8h, Oacc[dt], 0, 0, 0);
        __builtin_amdgcn_s_setprio(0);
      }
    }
  }

#pragma unroll
  for (int r = 0; r < 16; ++r) {
    float t = lr[r];
    t += __shfl_xor(t, 1);
    t += __shfl_xor(t, 2);
    t += __shfl_xor(t, 4);
    t += __shfl_xor(t, 8);
    t += __shfl_xor(t, 16);
    lr[r] = t;
  }
  if (l31 == 0) {
#pragma unroll
    for (int r = 0; r < 16; ++r) lsh[w][rowq[r]] = lr[r];
  }
  if (w == 0) {
#pragma unroll
    for (int dt = 0; dt < 4; ++dt)
#pragma unroll
      for (int r = 0; r < 16; ++r) Osum[rowq[r] * 128 + dt * 32 + l31] = Oacc[dt][r];
  }
  __syncthreads();
  if (w == 1) {
#pragma unroll
    for (int dt = 0; dt < 4; ++dt)
#pragma unroll
      for (int r = 0; r < 16; ++r) Osum[rowq[r] * 128 + dt * 32 + l31] += Oacc[dt][r];
  }
  __syncthreads();
  if (w == 2) {
#pragma unroll
    for (int dt = 0; dt < 4; ++dt)
#pragma unroll
      for (int r = 0; r < 16; ++r) Osum[rowq[r] * 128 + dt * 32 + l31] += Oacc[dt][r];
  }
  __syncthreads();
  if (w == 3) {
#pragma unroll
    for (int dt = 0; dt < 4; ++dt)
#pragma unroll
      for (int r = 0; r < 16; ++r) Osum[rowq[r] * 128 + dt * 32 + l31] += Oacc[dt][r];
  }
  __syncthreads();
  // ---- fused qdq epilogue (e5m2): one quant block per row ----
  const int row = w * 8 + (lane >> 3);
  const int c0 = (lane & 7) * 16;
  const float inv = 1.0f / (lsh[0][row] + lsh[1][row] + lsh[2][row] + lsh[3][row]);
  float vq[16];
  float am = 0.f;
#pragma unroll
  for (int i2 = 0; i2 < 4; ++i2) {
    float4 v = *(const float4*)(Osum + row * 128 + c0 + i2 * 4);
    vq[i2 * 4 + 0] = v.x * inv;
    vq[i2 * 4 + 1] = v.y * inv;
    vq[i2 * 4 + 2] = v.z * inv;
    vq[i2 * 4 + 3] = v.w * inv;
  }
#pragma unroll
  for (int t = 0; t < 16; ++t) am = fmaxf(am, fabsf(vq[t]));
  am = fmaxf(am, __shfl_xor(am, 1));
  am = fmaxf(am, __shfl_xor(am, 2));
  am = fmaxf(am, __shfl_xor(am, 4));
  const float sc = fmaxf(am / 57344.f, 1e-12f);
  uint8_t qb8[16];
#pragma unroll
  for (int t = 0; t < 16; ++t) qb8[t] = q_e5(vq[t], sc);
  const int token = b * 1024 + i0 + row;
  *(uint4*)(Aqo + (size_t)token * 2048 + hofs + c0) = *(const uint4*)qb8;
  if ((lane & 7) == 0) sTo[(size_t)(bh & 15) * 2048 + token] = sc;
}

// ---------------------------------------------------------------------------
// MX-fp8 GEMM (r0-proven simple structure): 128x128 tile, BK=128, single
// 32KB-buffer stage->sync->compute loop; 4 blocks/CU TLP (m114).
// EPI=0: f32 out (+opt bias/gelu).  EPI=1 (fc1): fused bias+gelu+e4m3 qdq.
// EPI=2 (qkv): emit Qh/Ql, Kh/Kl elementwise and Vth/Vtl TRANSPOSED via the
// LDS (dead after the main loop) as packed (hi|lo<<16) u32 — replaces the
// split_bf16 and vtrans kernels with identical bf16_rne math on identical
// f32 values (bit-identical attention inputs). FMT: 0 = e4m3fn, 1 = e5m2.
// ---------------------------------------------------------------------------
template <int FMT, int EPI>
__global__ __launch_bounds__(256, 2) void gemm_simple(
    const uint8_t* __restrict__ A, const float* __restrict__ sxT,
    const uint8_t* __restrict__ W, const float* __restrict__ wsc,
    const float* __restrict__ bias, float* __restrict__ out,
    uint8_t* __restrict__ outq, float* __restrict__ sTq,
    u16* __restrict__ Qh, u16* __restrict__ Ql,
    u16* __restrict__ Kh, u16* __restrict__ Kl,
    u16* __restrict__ Vth, u16* __restrict__ Vtl,
    int M, int N, int K, int gelu, int seg_shift, int Nw) {
  __shared__ uint8_t smem[33792];           // As | Ws | rowred, or tsm overlay
  uint8_t* As = smem;                       // 16384
  uint8_t* Ws = smem + 16384;               // 16384
  float* rowred = (float*)(smem + 32768);   // [2][128]
  uint32_t(*tsm)[66] = (uint32_t(*)[66])smem;  // 128x66 u32 = 33792 (EPI==2)

  const int tid = threadIdx.x;
  const int lane = tid & 63;
  const int wave = tid >> 6;
  const int wm = (wave >> 1) * 64;
  const int wn = (wave & 1) * 64;
  const int l31 = lane & 31;
  const int q2 = lane >> 5;
  const int bm = blockIdx.y * 128;
  const int bn = blockIdx.x * 128;

  // staging: instr s covers rows [s*32 + wave*8, +8); LDS dest = uniform +
  // lane*16 (required); global chunk XOR-swizzled so LDS chunk = orig^(row&7).
  const int srow = wave * 8 + (lane >> 3);
  const int gchunk = (lane & 7) ^ (lane >> 3);
  const uint8_t* ga = A + (size_t)(bm + srow) * K + gchunk * 16;
  const uint8_t* gw = W + (size_t)(bn + srow) * K + gchunk * 16;
  uint8_t* la = As + srow * 128 + (lane & 7) * 16;
  uint8_t* lw = Ws + srow * 128 + (lane & 7) * 16;

  const f32x16 z16 = {0.f};
  f32x16 acc[2][2] = {{z16, z16}, {z16, z16}};

  const int nk = K >> 7;
  for (int kt = 0; kt < nk; ++kt) {
    __syncthreads();
#pragma unroll
    for (int s = 0; s < 4; ++s) {
      gl_lds16(ga + (size_t)s * 32 * K, la + s * 4096);
      gl_lds16(gw + (size_t)s * 32 * K, lw + s * 4096);
    }
    ga += 128;
    gw += 128;
    __syncthreads();
    f32x16 chk[2][2] = {{z16, z16}, {z16, z16}};
#pragma unroll
    for (int mf = 0; mf < 2; ++mf) {  // two K=64 halves of the 128-K tile
      i32x8 af[2], bf2[2];
      const int c = mf * 4 + q2 * 2;  // lane's first 16B chunk (k = c*16)
#pragma unroll
      for (int i = 0; i < 2; ++i) {
        const int r = wm + i * 32 + l31;
        const uint8_t* Ar = As + r * 128;
        const int s7 = r & 7;
        af[i] = pack8(*(const uint4*)(Ar + ((c ^ s7) * 16)),
                      *(const uint4*)(Ar + (((c + 1) ^ s7) * 16)));
      }
#pragma unroll
      for (int j = 0; j < 2; ++j) {
        const int r = wn + j * 32 + l31;
        const uint8_t* Wr = Ws + r * 128;
        const int s7 = r & 7;
        bf2[j] = pack8(*(const uint4*)(Wr + ((c ^ s7) * 16)),
                       *(const uint4*)(Wr + (((c + 1) ^ s7) * 16)));
      }
#pragma unroll
      for (int i = 0; i < 2; ++i)
#pragma unroll
        for (int j = 0; j < 2; ++j)
          chk[i][j] = __builtin_amdgcn_mfma_scale_f32_32x32x64_f8f6f4(
              af[i], bf2[j], chk[i][j], FMT, FMT, 0, 0x7F7F7F7F, 0, 0x7F7F7F7F);
    }
    // fold the per-128-K activation scale (exact)
#pragma unroll
    for (int i = 0; i < 2; ++i) {
#pragma unroll
      for (int rg = 0; rg < 4; ++rg) {
        const f32x4 sv = *(const f32x4*)(sxT + (size_t)kt * M + bm + wm + i * 32 + rg * 8 + q2 * 4);
#pragma unroll
        for (int j = 0; j < 2; ++j)
#pragma unroll
          for (int rr = 0; rr < 4; ++rr)
            acc[i][j][rg * 4 + rr] += sv[rr] * chk[i][j][rg * 4 + rr];
      }
    }
  }

  if (EPI == 2) {
    // ---- fused qkv epilogue: Q/K split + V transpose via LDS ----
    const int seg = bn >> 11;        // 0=q 1=k 2=v
    const int col0 = bn & 2047;
    const int b = bm >> 10;
    const int t0g = bm & 1023;
    const int h = col0 >> 7;
#pragma unroll
    for (int p = 0; p < 2; ++p) {
      __syncthreads();  // also fences last K-tile's As/Ws reads before overlay
      if ((wave & 1) == p) {
#pragma unroll
        for (int i = 0; i < 2; ++i)
#pragma unroll
          for (int j = 0; j < 2; ++j) {
            const int n = bn + wn + j * 32 + l31;
            const float wsn = wsc[n >> 7];
            const int dloc = j * 32 + l31;
#pragma unroll
            for (int reg = 0; reg < 16; ++reg) {
              const int tl = wm + i * 32 + (reg & 3) + 8 * (reg >> 2) + 4 * q2;
              const float v = acc[i][j][reg] * wsn;
              const u16 hv = bf16_rne(v);
              const u16 lv = bf16_rne(v - __uint_as_float((uint32_t)hv << 16));
              tsm[tl][dloc] = (uint32_t)hv | ((uint32_t)lv << 16);
            }
          }
      }
      __syncthreads();
      u16 hbuf[32], lbuf[32];
      if (seg < 2) {
        u16* OH = seg == 0 ? Qh : Kh;
        u16* OL = seg == 0 ? Ql : Kl;
        const int row = tid >> 1;
        const int cb = (tid & 1) * 32;
#pragma unroll
        for (int c = 0; c < 32; ++c) {
          const uint32_t pk = tsm[row][cb + c];
          hbuf[c] = (u16)pk;
          lbuf[c] = (u16)(pk >> 16);
        }
        const size_t ob = (size_t)(bm + row) * 2048 + col0 + p * 64 + cb;
#pragma unroll
        for (int c = 0; c < 4; ++c) {
          *(uint4*)(OH + ob + c * 8) = *(const uint4*)(hbuf + c * 8);
          *(uint4*)(OL + ob + c * 8) = *(const uint4*)(lbuf + c * 8);
        }
      } else {
        const int d = p * 64 + (tid >> 2);
        const int toff = (tid & 3) * 32;
#pragma unroll
        for (int c = 0; c < 32; ++c) {
          const uint32_t pk = tsm[toff + c][tid >> 2];
          hbuf[c] = (u16)pk;
          lbuf[c] = (u16)(pk >> 16);
        }
        const size_t ob = ((size_t)((b * 16 + h) * 128 + d)) * 1024 + t0g + toff;
#pragma unroll
        for (int c = 0; c < 4; ++c) {
          *(uint4*)(Vth + ob + c * 8) = *(const uint4*)(hbuf + c * 8);
          *(uint4*)(Vtl + ob + c * 8) = *(const uint4*)(lbuf + c * 8);
        }
      }
    }
    return;
  }

  if (EPI == 1) {
    // ---- fused bias+gelu+qdq epilogue (e4m3; fc1) ----
#pragma unroll
    for (int i = 0; i < 2; ++i) {
#pragma unroll
      for (int j = 0; j < 2; ++j) {
        const int n = bn + wn + j * 32 + l31;
        const float wsn = wsc[n >> 7];
        const float bv = bias[n];
#pragma unroll
        for (int reg = 0; reg < 16; ++reg) {
          float v = acc[i][j][reg] * wsn + bv;
          acc[i][j][reg] = 0.5f * v * (1.f + erff(v * 0.70710678118654752440f));
        }
      }
    }
    // per-row absmax over the 128-wide tile (= one quant block)
#pragma unroll
    for (int i = 0; i < 2; ++i) {
      float am2[16];
#pragma unroll
      for (int reg = 0; reg < 16; ++reg)
        am2[reg] = fmaxf(fabsf(acc[i][0][reg]), fabsf(acc[i][1][reg]));
#pragma unroll
      for (int reg = 0; reg < 16; ++reg) {
        am2[reg] = fmaxf(am2[reg], __shfl_xor(am2[reg], 1));
        am2[reg] = fmaxf(am2[reg], __shfl_xor(am2[reg], 2));
        am2[reg] = fmaxf(am2[reg], __shfl_xor(am2[reg], 4));
        am2[reg] = fmaxf(am2[reg], __shfl_xor(am2[reg], 8));
        am2[reg] = fmaxf(am2[reg], __shfl_xor(am2[reg], 16));
      }
      if (l31 == 0) {
#pragma unroll
        for (int reg = 0; reg < 16; ++reg)
          rowred[(wave & 1) * 128 + wm + i * 32 + (reg & 3) + 8 * (reg >> 2) + 4 * q2] = am2[reg];
      }
    }
    __syncthreads();
#pragma unroll
    for (int i = 0; i < 2; ++i) {
#pragma unroll
      for (int reg = 0; reg < 16; ++reg) {
        const int rloc = wm + i * 32 + (reg & 3) + 8 * (reg >> 2) + 4 * q2;
        const float sc = fmaxf(fmaxf(rowred[rloc], rowred[128 + rloc]) / 448.f, 1e-12f);
        const int m = bm + rloc;
#pragma unroll
        for (int j = 0; j < 2; ++j)
          outq[(size_t)m * N + bn + wn + j * 32 + l31] = q_e4(acc[i][j][reg], sc);
        if ((wave & 1) == 0 && l31 == 0) sTq[(size_t)(bn >> 7) * M + m] = sc;
      }
    }
    return;
  }

#pragma unroll
  for (int i = 0; i < 2; ++i) {
#pragma unroll
    for (int j = 0; j < 2; ++j) {
      const int n = bn + wn + j * 32 + l31;
      const float wsn = wsc[n >> 7];
      const float bv = bias ? bias[n] : 0.f;
      const int seg = n >> seg_shift;
      const int col = n & ((1 << seg_shift) - 1);
      float* op = out + (size_t)seg * M * Nw + col;
#pragma unroll
      for (int reg = 0; reg < 16; ++reg) {
        const int m = bm + wm + i * 32 + (reg & 3) + 8 * (reg >> 2) + 4 * q2;
        float v = acc[i][j][reg] * wsn + bv;
        if (gelu) v = 0.5f * v * (1.f + erff(v * 0.70710678118654752440f));
        op[(size_t)m * Nw] = v;
      }
    }
  }
}

// out = LN(a + b) * (g*gs_rep) + (bb*bs_rep), eps=1e-5, C=2048, one block/row.
// QOUT=1 additionally quantizes the output (e4m3, 16 blocks/row) and writes
// fp8 bytes + transposed scales — removes the standalone qdq(ln1o) pass.
template <int QOUT>
__global__ __launch_bounds__(256) void ln_kernel(
    const float* __restrict__ a, const float* __restrict__ b2,
    const float* __restrict__ g, const float* __restrict__ gs,
    const float* __restrict__ bb, const float* __restrict__ bs,
    float* __restrict__ out, uint8_t* __restrict__ outq, float* __restrict__ sT,
    int C) {
  __shared__ float red[4];
  __shared__ float wred[8][4];
  const int tid = threadIdx.x;
  const int row = blockIdx.x;
  const float* pa = a + (size_t)row * C;
  const float* pb = b2 + (size_t)row * C;
  float v[8];
  float sum = 0.f;
#pragma unroll
  for (int k = 0; k < 8; ++k) {
    const int c = tid + (k << 8);
    v[k] = pa[c] + pb[c];
    sum += v[k];
  }
#pragma unroll
  for (int m = 32; m >= 1; m >>= 1) sum += __shfl_xor(sum, m);
  if ((tid & 63) == 0) red[tid >> 6] = sum;
  __syncthreads();
  const float mean = (red[0] + red[1] + red[2] + red[3]) * (1.f / 2048.f);
  __syncthreads();
  float sq = 0.f;
#pragma unroll
  for (int k = 0; k < 8; ++k) {
    const float d = v[k] - mean;
    sq += d * d;
  }
#pragma unroll
  for (int m = 32; m >= 1; m >>= 1) sq += __shfl_xor(sq, m);
  if ((tid & 63) == 0) red[tid >> 6] = sq;
  __syncthreads();
  const float var = (red[0] + red[1] + red[2] + red[3]) * (1.f / 2048.f);
  const float inv = 1.0f / sqrtf(var + 1e-5f);
  float* po = out + (size_t)row * C;
  float o[8];
#pragma unroll
  for (int k = 0; k < 8; ++k) {
    const int c = tid + (k << 8);
    o[k] = (v[k] - mean) * inv * (g[c] * gs[c >> 7]) + bb[c] * bs[c >> 7];
    po[c] = o[k];
  }
  if (QOUT) {
    const int w = tid >> 6;
#pragma unroll
    for (int k = 0; k < 8; ++k) {
      float am = fabsf(o[k]);
      am = fmaxf(am, __shfl_xor(am, 1));
      am = fmaxf(am, __shfl_xor(am, 2));
      am = fmaxf(am, __shfl_xor(am, 4));
      am = fmaxf(am, __shfl_xor(am, 8));
      am = fmaxf(am, __shfl_xor(am, 16));
      am = fmaxf(am, __shfl_xor(am, 32));
      if ((tid & 63) == 0) wred[k][w] = am;
    }
    __syncthreads();
    const int hsel = (tid >> 7) * 2;
#pragma unroll
    for (int k = 0; k < 8; ++k) {
      const float bm = fmaxf(wred[k][hsel], wred[k][hsel + 1]);
      const float sc = fmaxf(bm / 448.f, 1e-12f);
      const int c = tid + (k << 8);
      outq[(size_t)row * C + c] = q_e4(o[k], sc);
      if ((tid & 127) == 0) sT[(size_t)((k << 1) | (tid >> 7)) * 2048 + row] = sc;
    }
  }
}

extern "C" void kernel_launch(void* const* d_in, const int* in_sizes, int n_in,
                              void* d_out, int out_size, void* d_ws, size_t ws_size,
                              hipStream_t stream) {
  const int C = 2048, MLP = 8192;
  const int M = 2048;  // B*T tokens

  const float* x = (const float*)d_in[0];
  const float* wq = (const float*)d_in[2];
  const float* qs = (const float*)d_in[3];
  const float* wk = (const float*)d_in[4];
  const float* ks = (const float*)d_in[5];
  const float* wv = (const float*)d_in[6];
  const float* vs = (const float*)d_in[7];
  const float* wo = (const float*)d_in[8];
  const float* os_ = (const float*)d_in[9];
  const float* fc1_w = (const float*)d_in[10];
  const float* fc1_s = (const float*)d_in[11];
  const float* fc1_b = (const float*)d_in[12];
  const float* fc2_w = (const float*)d_in[13];
  const float* fc2_s = (const float*)d_in[14];
  const float* fc2_b = (const float*)d_in[15];
  const float* ln1_g = (const float*)d_in[16];
  const float* ln1_gs = (const float*)d_in[17];
  const float* ln1_b = (const float*)d_in[18];
  const float* ln1_bs = (const float*)d_in[19];
  const float* ln2_g = (const float*)d_in[20];
  const float* ln2_gs = (const float*)d_in[21];
  const float* ln2_b = (const float*)d_in[22];
  const float* ln2_bs = (const float*)d_in[23];

  char* ws = (char*)d_ws;
  const size_t o_Aq = 0;           // 32 MB
  const size_t o_Wb = 33554432;    // 32 MB fp8 weights
  const size_t o_sx = 67108864;    // 512 KB activation scales (transposed)
  const size_t o_ln1 = 67633152;   // 16 MB
  const size_t o_q = 84410368;     // 16 MB: Qh | Ql (u16 each 8 MB)
  const size_t o_k = 101187584;    // 16 MB: Kh | Kl
  const size_t o_v = 117964800;    // 16 MB: Vth | Vtl
  const size_t o_ctx = 134742016;  // 16 MB (attn fused fp8 out: 4 MB used)
  const size_t o_attn = 151519232; // 16 MB -> end 168296448
  const size_t o_ffn = o_attn;     // ffn reuses attn_out (dead by fc2)
  if (ws_size < 168296448ull) return;

  uint8_t* Aq = (uint8_t*)(ws + o_Aq);        // qdq(x) out; later ln1-fused out
  uint8_t* Wb = (uint8_t*)(ws + o_Wb);
  float* sx = (float*)(ws + o_sx);
  float* wsc3 = (float*)(ws + o_sx + 262144); // dead part of sx region during qkv
  float* ln1o = (float*)(ws + o_ln1);
  u16* Qh = (u16*)(ws + o_q);
  u16* Ql = (u16*)(ws + o_q + 8388608);
  u16* Kh = (u16*)(ws + o_k);
  u16* Kl = (u16*)(ws + o_k + 8388608);
  u16* Vth = (u16*)(ws + o_v);
  u16* Vtl = (u16*)(ws + o_v + 8388608);
  uint8_t* Aq2 = (uint8_t*)(ws + o_ctx);      // attn fused fp8 out (4 MB)
  float* attn_out = (float*)(ws + o_attn);
  uint8_t* Aq3 = (uint8_t*)(ws + o_q);        // fc1 fused fp8 out (16 MB; Q dead)
  float* sxk = (float*)(ws + o_k);            // fc2 A-scales (512 KB; K dead)
  float* ffn = (float*)(ws + o_ffn);
  float* outp = (float*)d_out;

  const float E5_MAX = 57344.f, E5_MINN = 6.103515625e-05f, E5_SUBQ = 1.52587890625e-05f;

  const dim3 blk(256);
  const int wc_qkv = (C * C / 4 + 255) / 256;
  const int wc_fc = (C * MLP / 4 + 255) / 256;

  // ---- fused qkv projection (e5m2 = fmt 1): one GEMM (N=6144) with fused
  //      Q/K-split + V-transpose epilogue ----
  qdq_kernel<<<M * (C / 128) / 4, blk, 0, stream>>>(x, Aq, sx, M * (C / 128), 4, E5_MAX, E5_MINN, E5_SUBQ, 2, 15);
  w3_to_fp8_kernel<<<dim3(wc_qkv, 3), blk, 0, stream>>>(wq, wk, wv, Wb, C * C / 4);
  concat3_kernel<<<1, 64, 0, stream>>>(qs, ks, vs, wsc3, C / 128);
  gemm_simple<1, 2><<<dim3(3 * C / 128, M / 128), blk, 0, stream>>>(
      Aq, sx, Wb, wsc3, nullptr, nullptr, nullptr, nullptr,
      Qh, Ql, Kh, Kl, Vth, Vtl, M, 3 * C, C, 0, 11, C);

  // ---- attention (bf16x3 MFMA flash; fused e5m2 qdq epilogue) ----
  attn_wave_kernel<<<dim3(32, 32), blk, 0, stream>>>(Qh, Ql, Kh, Kl, Vth, Vtl, Aq2, sx);

  // ---- attn-out projection (reads fused fp8 ctx directly) ----
  w_to_fp8_kernel<<<wc_qkv, blk, 0, stream>>>(wo, Wb, C * C / 4, 2, 15);
  gemm_simple<1, 0><<<dim3(C / 128, M / 128), blk, 0, stream>>>(
      Aq2, sx, Wb, os_, nullptr, attn_out, nullptr, nullptr,
      nullptr, nullptr, nullptr, nullptr, nullptr, nullptr, M, C, C, 0, 30, C);

  // ---- ln1 (fused e4m3 qdq: emits fc1's A + scales directly) ----
  ln_kernel<1><<<M, blk, 0, stream>>>(x, attn_out, ln1_g, ln1_gs, ln1_b, ln1_bs,
                                      ln1o, Aq, sx, C);

  // ---- MLP (e4m3fn = fmt 0) ----
  w_to_fp8_kernel<<<wc_fc, blk, 0, stream>>>(fc1_w, Wb, C * MLP / 4, 3, 7);
  // fc1 with fused bias+gelu+qdq epilogue: writes fp8 Aq3 + sxk, no f32 hb
  gemm_simple<0, 1><<<dim3(MLP / 128, M / 128), blk, 0, stream>>>(
      Aq, sx, Wb, fc1_s, fc1_b, nullptr, Aq3, sxk,
      nullptr, nullptr, nullptr, nullptr, nullptr, nullptr, M, MLP, C, 1, 30, MLP);

  w_to_fp8_kernel<<<wc_fc, blk, 0, stream>>>(fc2_w, Wb, C * MLP / 4, 3, 7);
  gemm_simple<0, 0><<<dim3(C / 128, M / 128), blk, 0, stream>>>(
      Aq3, sxk, Wb, fc2_s, fc2_b, ffn, nullptr, nullptr,
      nullptr, nullptr, nullptr, nullptr, nullptr, nullptr, M, C, MLP, 0, 30, C);

  ln_kernel<0><<<M, blk, 0, stream>>>(ln1o, ffn, ln2_g, ln2_gs, ln2_b, ln2_bs,
                                      outp, nullptr, nullptr, C);
}